// Round 7
// baseline (241.299 us; speedup 1.0000x reference)
//
#include <hip/hip_runtime.h>

// NSA constants
#define NCMP 127
#define SCALE 0.08838834764831845f
#define QSCALE (0.08838834764831845f * 1.4426950408889634f)  // SCALE * log2(e)
#define TB 8    // t's per WG in k_cmp_attn

typedef __attribute__((ext_vector_type(8))) short bf16x8;
typedef __attribute__((ext_vector_type(4))) float f32x4;

__device__ __forceinline__ unsigned short f2bf(float x) {
    union { float f; unsigned u; } a; a.f = x;
    unsigned r = a.u + 0x7fffu + ((a.u >> 16) & 1u);
    return (unsigned short)(r >> 16);
}
__device__ __forceinline__ float dot4(float4 a, float4 b) {
    return a.x * b.x + a.y * b.y + a.z * b.z + a.w * b.w;
}

// ------------- Kernel A: fused k+v compress (gate-pooled blocks) -------------
__global__ __launch_bounds__(256) void k_compress2(const float* __restrict__ kk,
                                                   const float* __restrict__ vv,
                                                   const float* __restrict__ wk,
                                                   const float* __restrict__ wv,
                                                   float* __restrict__ ck,
                                                   float* __restrict__ cv) {
    __shared__ float blk[4096];   // 32 x 128 f32
    __shared__ float gate[32];
    int n = blockIdx.x >> 1;
    int which = blockIdx.x & 1;
    const float* src = which ? vv : kk;
    const float* w   = which ? wv : wk;
    float* out       = which ? cv : ck;
    int tid = threadIdx.x;

    {
        const float4* sp = reinterpret_cast<const float4*>(src + n * 16 * 128);
        float4* bp = reinterpret_cast<float4*>(blk);
        #pragma unroll
        for (int i = 0; i < 4; ++i) bp[tid + 256 * i] = sp[tid + 256 * i];
    }
    __syncthreads();

    {
        int j = tid >> 3, sub = tid & 7;
        const float4* wp = reinterpret_cast<const float4*>(w + j * 4096);
        const float4* bp = reinterpret_cast<const float4*>(blk);
        float s0 = 0.f, s1 = 0.f, s2 = 0.f, s3 = 0.f;
        for (int i = sub * 4; i < 1024; i += 32) {
            float4 w0 = wp[i], w1 = wp[i + 1], w2 = wp[i + 2], w3 = wp[i + 3];
            s0 += dot4(bp[i], w0);
            s1 += dot4(bp[i + 1], w1);
            s2 += dot4(bp[i + 2], w2);
            s3 += dot4(bp[i + 3], w3);
        }
        float s = (s0 + s1) + (s2 + s3);
        s += __shfl_xor(s, 1);
        s += __shfl_xor(s, 2);
        s += __shfl_xor(s, 4);
        if (sub == 0) gate[j] = s;
    }
    __syncthreads();

    if (tid < 32) {
        float gv = gate[tid];
        float m = gv;
        #pragma unroll
        for (int off = 16; off > 0; off >>= 1) m = fmaxf(m, __shfl_xor(m, off));
        float e = expf(gv - m);
        float ss = e;
        #pragma unroll
        for (int off = 16; off > 0; off >>= 1) ss += __shfl_xor(ss, off);
        gate[tid] = e / ss;
    }
    __syncthreads();

    if (tid < 128) {
        float acc = 0.f;
        #pragma unroll
        for (int kx = 0; kx < 32; ++kx) acc += gate[kx] * blk[kx * 128 + tid];
        out[n * 128 + tid] = acc;
    }
}

// ------------- Kernel D: f32 -> bf16 convert (K row-major, V transposed) -------------
__global__ __launch_bounds__(256) void k_convert(const float* __restrict__ k,
                                                 const float* __restrict__ v,
                                                 unsigned short* __restrict__ kbf,
                                                 unsigned short* __restrict__ vtbf) {
    int bid = blockIdx.x, tid = threadIdx.x;
    {
        int idx = bid * 1024 + tid * 4;
        float4 x = *reinterpret_cast<const float4*>(k + idx);
        unsigned short o[4] = {f2bf(x.x), f2bf(x.y), f2bf(x.z), f2bf(x.w)};
        *reinterpret_cast<ulonglong1*>(kbf + idx) = *reinterpret_cast<ulonglong1*>(o);
    }
    {
        int p = bid * 8 + (tid >> 5);
        int d4 = (tid & 31) << 2;
        float4 x = *reinterpret_cast<const float4*>(v + p * 128 + d4);
        vtbf[(d4 + 0) * 2048 + p] = f2bf(x.x);
        vtbf[(d4 + 1) * 2048 + p] = f2bf(x.y);
        vtbf[(d4 + 2) * 2048 + p] = f2bf(x.z);
        vtbf[(d4 + 3) * 2048 + p] = f2bf(x.w);
    }
}

// ---------- Kernel B: compressed attention + top-k block select ----------
__global__ __launch_bounds__(256) void k_cmp_attn(const float* __restrict__ q,
                                                  const float* __restrict__ ck,
                                                  const float* __restrict__ cv,
                                                  float* __restrict__ o_cmp,
                                                  unsigned int* __restrict__ selmask) {
    __shared__ float sc[64 * 132];
    __shared__ float pg[TB * 128];
    __shared__ float slc[TB * 32];
    __shared__ float adj[TB * 32];
    int t0 = blockIdx.x * TB;
    int tid = threadIdx.x;
    int wv = tid >> 6, ln = tid & 63;

    {
        int rh = wv >> 1, nh = wv & 1;
        int rg = ln >> 3, ds = ln & 7;
        int d0 = ds * 16;
        float4 qr[4][4];
        #pragma unroll
        for (int rr = 0; rr < 4; ++rr) {
            int r = rh * 32 + rg * 4 + rr;
            const float4* qp = reinterpret_cast<const float4*>(
                q + (t0 + (r >> 3)) * 1024 + (r & 7) * 128 + d0);
            #pragma unroll
            for (int cc = 0; cc < 4; ++cc) qr[rr][cc] = qp[cc];
        }
        for (int jn = 0; jn < 64; ++jn) {
            int n = nh * 64 + jn;
            if (n >= NCMP) break;
            const float4* kp = reinterpret_cast<const float4*>(ck + n * 128 + d0);
            float4 k0 = kp[0], k1 = kp[1], k2 = kp[2], k3 = kp[3];
            float part[4];
            #pragma unroll
            for (int rr = 0; rr < 4; ++rr)
                part[rr] = dot4(qr[rr][0], k0) + dot4(qr[rr][1], k1) +
                           dot4(qr[rr][2], k2) + dot4(qr[rr][3], k3);
            #pragma unroll
            for (int off = 1; off < 8; off <<= 1)
                #pragma unroll
                for (int rr = 0; rr < 4; ++rr) part[rr] += __shfl_xor(part[rr], off);
            if (ds == 0) {
                #pragma unroll
                for (int rr = 0; rr < 4; ++rr)
                    sc[(rh * 32 + rg * 4 + rr) * 132 + n] = part[rr] * SCALE;
            }
        }
    }
    __syncthreads();

    {
        int r = wv * 16 + (ln >> 2);
        int nl = ln & 3;
        int t = t0 + (r >> 3);
        int nvalid = (t >= 31) ? (((t - 31) >> 4) + 1) : 0;
        if (nvalid > NCMP) nvalid = NCMP;
        float* row = sc + r * 132;
        float m = -3e38f;
        for (int n = nl; n < nvalid; n += 4) m = fmaxf(m, row[n]);
        m = fmaxf(m, __shfl_xor(m, 1));
        m = fmaxf(m, __shfl_xor(m, 2));
        float ss = 0.f;
        for (int n = nl; n < 128; n += 4) {
            float e = (n < nvalid) ? expf(row[n] - m) : 0.f;
            ss += e;
            row[n] = e;
        }
        ss += __shfl_xor(ss, 1);
        ss += __shfl_xor(ss, 2);
        float inv = (ss > 0.f) ? 1.f / ss : 0.f;
        for (int n = nl; n < 128; n += 4) row[n] *= inv;
    }
    __syncthreads();

    {
        int rg = ln >> 3, ds = ln & 7, d0 = ds * 16;
        int rbase = wv * 16 + rg * 2;
        int nvmax = (t0 + 7 >= 31) ? (((t0 + 7 - 31) >> 4) + 1) : 0;
        if (nvmax > NCMP) nvmax = NCMP;
        float4 acc[2][4];
        #pragma unroll
        for (int rr = 0; rr < 2; ++rr)
            #pragma unroll
            for (int cc = 0; cc < 4; ++cc) acc[rr][cc] = (float4){0.f, 0.f, 0.f, 0.f};
        for (int n = 0; n < nvmax; ++n) {
            const float4* vp = reinterpret_cast<const float4*>(cv + n * 128 + d0);
            float4 v0 = vp[0], v1 = vp[1], v2 = vp[2], v3 = vp[3];
            #pragma unroll
            for (int rr = 0; rr < 2; ++rr) {
                float p = sc[(rbase + rr) * 132 + n];
                acc[rr][0].x += p * v0.x; acc[rr][0].y += p * v0.y; acc[rr][0].z += p * v0.z; acc[rr][0].w += p * v0.w;
                acc[rr][1].x += p * v1.x; acc[rr][1].y += p * v1.y; acc[rr][1].z += p * v1.z; acc[rr][1].w += p * v1.w;
                acc[rr][2].x += p * v2.x; acc[rr][2].y += p * v2.y; acc[rr][2].z += p * v2.z; acc[rr][2].w += p * v2.w;
                acc[rr][3].x += p * v3.x; acc[rr][3].y += p * v3.y; acc[rr][3].z += p * v3.z; acc[rr][3].w += p * v3.w;
            }
        }
        #pragma unroll
        for (int rr = 0; rr < 2; ++rr) {
            int r = rbase + rr;
            float4* op = reinterpret_cast<float4*>(
                o_cmp + (t0 + (r >> 3)) * 1024 + (r & 7) * 128 + d0);
            #pragma unroll
            for (int cc = 0; cc < 4; ++cc) op[cc] = acc[rr][cc];
        }
    }

    for (int i2 = tid; i2 < TB * 128; i2 += 256) {
        int tl = i2 >> 7, n = i2 & 127;
        float s = 0.f;
        #pragma unroll
        for (int h = 0; h < 8; ++h) s += sc[(tl * 8 + h) * 132 + n];
        pg[i2] = s;
    }
    __syncthreads();
    if (tid < TB * 32) {
        int tl = tid >> 5, s32 = tid & 31;
        float s = 0.f;
        #pragma unroll
        for (int j = 0; j < 4; ++j) {
            int n = s32 * 4 + j;
            if (n < NCMP) s += pg[tl * 128 + n];
        }
        slc[tid] = s;
    }
    __syncthreads();
    if (tid < TB) {
        int t = t0 + tid;
        int qblk = t >> 6;
        float* a = adj + tid * 32;
        for (int s = 0; s < 32; ++s) {
            if (s > qblk) a[s] = -1e30f;
            else a[s] = slc[tid * 32 + s] + ((s == 0 || s > qblk - 2) ? 1e30f : 0.f);
        }
        unsigned int msk = 0u;
        for (int it = 0; it < 16; ++it) {
            float best = -2e38f; int bi = 0;
            for (int s = 0; s < 32; ++s) { if (a[s] > best) { best = a[s]; bi = s; } }
            if (best <= -5e29f) break;
            msk |= 1u << bi;
            a[bi] = -2e38f;
        }
        selmask[t] = msk;
    }
}

// -------- Kernel C: branch-fused, 4-way split-K over sel-union-win blocks --------
__global__ __launch_bounds__(256, 3) void k_main(const float* __restrict__ q,
                                              const unsigned short* __restrict__ kbf,
                                              const unsigned short* __restrict__ vtbf,
                                              const unsigned int* __restrict__ selmask,
                                              const float* __restrict__ fw,
                                              float* __restrict__ out) {
    __shared__ float mrg[4][16 * 132];             // 4 publish buffers (2 waves x 2 branches)
    __shared__ float mlbuf[4][2][16][2];           // wave, br, row, {m,l}

    // swizzle: the 4 WGs co-resident on a CU span a 768-t range (balance)
    int bid = blockIdx.x;
    int pairidx = ((bid & 3) << 8) | (bid >> 2);
    int tp = pairidx * 2;

    int tid = threadIdx.x;
    int wv = tid >> 6, ln = tid & 63;
    int c = ln & 15, g = ln >> 4;

    unsigned int sm0 = selmask[tp], sm1 = selmask[tp + 1];
    unsigned int sm_wave = sm0 | sm1;

    // per-lane q-row: row = c -> t = tp + (c>>3), h = c&7
    int th = tp + (c >> 3);
    int hh = c & 7;
    unsigned int smc = (c >> 3) ? sm1 : sm0;

    // Q fragments (B-operand for swapped QK), pre-scaled to log2 domain
    bf16x8 qf[4];
    {
        const float* qp = q + th * 1024 + hh * 128;
        #pragma unroll
        for (int ks = 0; ks < 4; ++ks) {
            int d0 = ks * 32 + g * 8;
            float4 x = *reinterpret_cast<const float4*>(qp + d0);
            float4 y = *reinterpret_cast<const float4*>(qp + d0 + 4);
            bf16x8 f;
            f[0]=(short)f2bf(x.x*QSCALE); f[1]=(short)f2bf(x.y*QSCALE); f[2]=(short)f2bf(x.z*QSCALE); f[3]=(short)f2bf(x.w*QSCALE);
            f[4]=(short)f2bf(y.x*QSCALE); f[5]=(short)f2bf(y.y*QSCALE); f[6]=(short)f2bf(y.z*QSCALE); f[7]=(short)f2bf(y.w*QSCALE);
            qf[ks] = f;
        }
    }

    float m_s = -1e30f, l_s = 0.f, m_w = -1e30f, l_w = 0.f;
    f32x4 o_s[8], o_w[8];
    #pragma unroll
    for (int dt = 0; dt < 8; ++dt) {
        o_s[dt] = (f32x4){0.f, 0.f, 0.f, 0.f};
        o_w[dt] = (f32x4){0.f, 0.f, 0.f, 0.f};
    }

    int qblk_max = (tp + 1) >> 6;
    int wlo = (tp >= 575) ? (((tp - 575) >> 6) + 1) : 0;
    unsigned int all = (qblk_max >= 31) ? 0xFFFFFFFFu : ((1u << (qblk_max + 1)) - 1u);
    unsigned int wmask = all & ~((1u << wlo) - 1u);
    unsigned int mm = (sm_wave & all) | wmask;     // union block list

    int srcA = ((g & 1) << 5) + c;
    int srcB = srcA + 16;
    bool hi = (g >= 2);

    int idx = 0;
    while (mm) {
        int b = __builtin_ctz(mm);
        mm &= mm - 1;
        if ((idx++ & 3) != wv) continue;

        bool s_act = (sm_wave >> b) & 1u;
        bool w_act = ((unsigned)(b * 64 + 575) > (unsigned)tp);
        bool selbit = (smc >> b) & 1u;

        // QK^T once per union block (swapped: S[qrow=c][pos])
        f32x4 sacc[4];
        #pragma unroll
        for (int nt = 0; nt < 4; ++nt) {
            f32x4 acc = (f32x4){0.f, 0.f, 0.f, 0.f};
            #pragma unroll
            for (int ks = 0; ks < 4; ++ks) {
                bf16x8 bfK = *reinterpret_cast<const bf16x8*>(
                    kbf + (b * 64 + nt * 16 + c) * 128 + ks * 32 + g * 8);
                acc = __builtin_amdgcn_mfma_f32_16x16x32_bf16(bfK, qf[ks], acc, 0, 0, 0);
            }
            sacc[nt] = acc;
        }

        unsigned int pw_s[8], pw_w[8];

        // ---- select softmax ----
        if (s_act) {
            float mloc = -1e30f;
            #pragma unroll
            for (int nt = 0; nt < 4; ++nt)
                #pragma unroll
                for (int i = 0; i < 4; ++i) {
                    int pos = b * 64 + nt * 16 + g * 4 + i;
                    bool val = selbit && (pos <= th);
                    float s = val ? sacc[nt][i] : -1e30f;
                    mloc = fmaxf(mloc, s);
                }
            mloc = fmaxf(mloc, __shfl_xor(mloc, 16));
            mloc = fmaxf(mloc, __shfl_xor(mloc, 32));
            float mn = fmaxf(m_s, mloc);
            float al = exp2f(m_s - mn);
            float lsum = 0.f;
            #pragma unroll
            for (int nt = 0; nt < 4; ++nt) {
                float pp[4];
                #pragma unroll
                for (int i = 0; i < 4; ++i) {
                    int pos = b * 64 + nt * 16 + g * 4 + i;
                    bool val = selbit && (pos <= th);
                    float p = val ? exp2f(sacc[nt][i] - mn) : 0.f;
                    pp[i] = p;
                    lsum += p;
                }
                asm("v_cvt_pk_bf16_f32 %0, %1, %2" : "=v"(pw_s[2*nt]) : "v"(pp[0]), "v"(pp[1]));
                asm("v_cvt_pk_bf16_f32 %0, %1, %2" : "=v"(pw_s[2*nt+1]) : "v"(pp[2]), "v"(pp[3]));
            }
            lsum += __shfl_xor(lsum, 16);
            lsum += __shfl_xor(lsum, 32);
            m_s = mn;
            l_s = l_s * al + lsum;
            if (__any(al != 1.f)) {
                #pragma unroll
                for (int dt = 0; dt < 8; ++dt)
                    #pragma unroll
                    for (int i = 0; i < 4; ++i)
                        o_s[dt][i] *= al;
            }
        }

        // ---- window softmax ----
        if (w_act) {
            float mloc = -1e30f;
            #pragma unroll
            for (int nt = 0; nt < 4; ++nt)
                #pragma unroll
                for (int i = 0; i < 4; ++i) {
                    int pos = b * 64 + nt * 16 + g * 4 + i;
                    bool val = (pos <= th) && (pos + 512 > th);
                    float s = val ? sacc[nt][i] : -1e30f;
                    mloc = fmaxf(mloc, s);
                }
            mloc = fmaxf(mloc, __shfl_xor(mloc, 16));
            mloc = fmaxf(mloc, __shfl_xor(mloc, 32));
            float mn = fmaxf(m_w, mloc);
            float al = exp2f(m_w - mn);
            float lsum = 0.f;
            #pragma unroll
            for (int nt = 0; nt < 4; ++nt) {
                float pp[4];
                #pragma unroll
                for (int i = 0; i < 4; ++i) {
                    int pos = b * 64 + nt * 16 + g * 4 + i;
                    bool val = (pos <= th) && (pos + 512 > th);
                    float p = val ? exp2f(sacc[nt][i] - mn) : 0.f;
                    pp[i] = p;
                    lsum += p;
                }
                asm("v_cvt_pk_bf16_f32 %0, %1, %2" : "=v"(pw_w[2*nt]) : "v"(pp[0]), "v"(pp[1]));
                asm("v_cvt_pk_bf16_f32 %0, %1, %2" : "=v"(pw_w[2*nt+1]) : "v"(pp[2]), "v"(pp[3]));
            }
            lsum += __shfl_xor(lsum, 16);
            lsum += __shfl_xor(lsum, 32);
            m_w = mn;
            l_w = l_w * al + lsum;
            if (__any(al != 1.f)) {
                #pragma unroll
                for (int dt = 0; dt < 8; ++dt)
                    #pragma unroll
                    for (int i = 0; i < 4; ++i)
                        o_w[dt][i] *= al;
            }
        }

        // ---- PV: V fragments loaded once, shared by both branches ----
        #pragma unroll
        for (int ks = 0; ks < 2; ++ks) {
            bf16x8 pa_s = {}, pa_w = {};
            if (s_act) {
                unsigned int a0 = __shfl(pw_s[4*ks+0], srcA);
                unsigned int a1 = __shfl(pw_s[4*ks+1], srcA);
                unsigned int a2 = __shfl(pw_s[4*ks+0], srcB);
                unsigned int a3 = __shfl(pw_s[4*ks+1], srcB);
                unsigned int b0 = __shfl(pw_s[4*ks+2], srcA);
                unsigned int b1 = __shfl(pw_s[4*ks+3], srcA);
                unsigned int b2 = __shfl(pw_s[4*ks+2], srcB);
                unsigned int b3 = __shfl(pw_s[4*ks+3], srcB);
                unsigned int wp[4] = {hi ? b0 : a0, hi ? b1 : a1, hi ? b2 : a2, hi ? b3 : a3};
                pa_s = *reinterpret_cast<bf16x8*>(wp);
            }
            if (w_act) {
                unsigned int a0 = __shfl(pw_w[4*ks+0], srcA);
                unsigned int a1 = __shfl(pw_w[4*ks+1], srcA);
                unsigned int a2 = __shfl(pw_w[4*ks+0], srcB);
                unsigned int a3 = __shfl(pw_w[4*ks+1], srcB);
                unsigned int b0 = __shfl(pw_w[4*ks+2], srcA);
                unsigned int b1 = __shfl(pw_w[4*ks+3], srcA);
                unsigned int b2 = __shfl(pw_w[4*ks+2], srcB);
                unsigned int b3 = __shfl(pw_w[4*ks+3], srcB);
                unsigned int wp[4] = {hi ? b0 : a0, hi ? b1 : a1, hi ? b2 : a2, hi ? b3 : a3};
                pa_w = *reinterpret_cast<bf16x8*>(wp);
            }
            #pragma unroll
            for (int dt = 0; dt < 8; ++dt) {
                bf16x8 bfV = *reinterpret_cast<const bf16x8*>(
                    vtbf + (dt * 16 + c) * 2048 + b * 64 + ks * 32 + g * 8);
                if (s_act) o_s[dt] = __builtin_amdgcn_mfma_f32_16x16x32_bf16(bfV, pa_s, o_s[dt], 0, 0, 0);
                if (w_act) o_w[dt] = __builtin_amdgcn_mfma_f32_16x16x32_bf16(bfV, pa_w, o_w[dt], 0, 0, 0);
            }
        }
    }

    // ---- merge: 2-step tree, both branches per publish ----
    if (g == 0) {
        mlbuf[wv][0][c][0] = m_s; mlbuf[wv][0][c][1] = l_s;
        mlbuf[wv][1][c][0] = m_w; mlbuf[wv][1][c][1] = l_w;
    }
    if (wv & 1) {
        int base = (wv >> 1) * 2;
        #pragma unroll
        for (int dt = 0; dt < 8; ++dt) {
            *reinterpret_cast<float4*>(&mrg[base][c * 132 + dt * 16 + g * 4]) =
                (float4){o_s[dt][0], o_s[dt][1], o_s[dt][2], o_s[dt][3]};
            *reinterpret_cast<float4*>(&mrg[base + 1][c * 132 + dt * 16 + g * 4]) =
                (float4){o_w[dt][0], o_w[dt][1], o_w[dt][2], o_w[dt][3]};
        }
    }
    __syncthreads();
    if (!(wv & 1)) {
        int base = (wv >> 1) * 2;
        {   // select
            float m1 = mlbuf[wv + 1][0][c][0], l1 = mlbuf[wv + 1][0][c][1];
            float mn = fmaxf(m_s, m1);
            float a0 = exp2f(m_s - mn), a1 = exp2f(m1 - mn);
            m_s = mn; l_s = a0 * l_s + a1 * l1;
            #pragma unroll
            for (int dt = 0; dt < 8; ++dt) {
                float4 o1 = *reinterpret_cast<const float4*>(&mrg[base][c * 132 + dt * 16 + g * 4]);
                o_s[dt][0] = a0 * o_s[dt][0] + a1 * o1.x;
                o_s[dt][1] = a0 * o_s[dt][1] + a1 * o1.y;
                o_s[dt][2] = a0 * o_s[dt][2] + a1 * o1.z;
                o_s[dt][3] = a0 * o_s[dt][3] + a1 * o1.w;
            }
        }
        {   // window
            float m1 = mlbuf[wv + 1][1][c][0], l1 = mlbuf[wv + 1][1][c][1];
            float mn = fmaxf(m_w, m1);
            float a0 = exp2f(m_w - mn), a1 = exp2f(m1 - mn);
            m_w = mn; l_w = a0 * l_w + a1 * l1;
            #pragma unroll
            for (int dt = 0; dt < 8; ++dt) {
                float4 o1 = *reinterpret_cast<const float4*>(&mrg[base + 1][c * 132 + dt * 16 + g * 4]);
                o_w[dt][0] = a0 * o_w[dt][0] + a1 * o1.x;
                o_w[dt][1] = a0 * o_w[dt][1] + a1 * o1.y;
                o_w[dt][2] = a0 * o_w[dt][2] + a1 * o1.z;
                o_w[dt][3] = a0 * o_w[dt][3] + a1 * o1.w;
            }
        }
    }
    __syncthreads();
    if (wv == 2) {
        if (g == 0) {
            mlbuf[2][0][c][0] = m_s; mlbuf[2][0][c][1] = l_s;
            mlbuf[2][1][c][0] = m_w; mlbuf[2][1][c][1] = l_w;
        }
        #pragma unroll
        for (int dt = 0; dt < 8; ++dt) {
            *reinterpret_cast<float4*>(&mrg[0][c * 132 + dt * 16 + g * 4]) =
                (float4){o_s[dt][0], o_s[dt][1], o_s[dt][2], o_s[dt][3]};
            *reinterpret_cast<float4*>(&mrg[1][c * 132 + dt * 16 + g * 4]) =
                (float4){o_w[dt][0], o_w[dt][1], o_w[dt][2], o_w[dt][3]};
        }
    }
    __syncthreads();
    if (wv != 0) return;

    {   // final merge of waves {2,3} into wave 0 — select
        float m1 = mlbuf[2][0][c][0], l1 = mlbuf[2][0][c][1];
        float mn = fmaxf(m_s, m1);
        float a0 = exp2f(m_s - mn), a1 = exp2f(m1 - mn);
        l_s = a0 * l_s + a1 * l1;
        #pragma unroll
        for (int dt = 0; dt < 8; ++dt) {
            float4 o1 = *reinterpret_cast<const float4*>(&mrg[0][c * 132 + dt * 16 + g * 4]);
            o_s[dt][0] = a0 * o_s[dt][0] + a1 * o1.x;
            o_s[dt][1] = a0 * o_s[dt][1] + a1 * o1.y;
            o_s[dt][2] = a0 * o_s[dt][2] + a1 * o1.z;
            o_s[dt][3] = a0 * o_s[dt][3] + a1 * o1.w;
        }
    }
    {   // window
        float m1 = mlbuf[2][1][c][0], l1 = mlbuf[2][1][c][1];
        float mn = fmaxf(m_w, m1);
        float a0 = exp2f(m_w - mn), a1 = exp2f(m1 - mn);
        l_w = a0 * l_w + a1 * l1;
        #pragma unroll
        for (int dt = 0; dt < 8; ++dt) {
            float4 o1 = *reinterpret_cast<const float4*>(&mrg[1][c * 132 + dt * 16 + g * 4]);
            o_w[dt][0] = a0 * o_w[dt][0] + a1 * o1.x;
            o_w[dt][1] = a0 * o_w[dt][1] + a1 * o1.y;
            o_w[dt][2] = a0 * o_w[dt][2] + a1 * o1.z;
            o_w[dt][3] = a0 * o_w[dt][3] + a1 * o1.w;
        }
    }
    // normalize both branches
    {
        float inv_s = 1.f / l_s, inv_w = 1.f / l_w;
        #pragma unroll
        for (int dt = 0; dt < 8; ++dt)
            #pragma unroll
            for (int i = 0; i < 4; ++i) {
                o_s[dt][i] *= inv_s;
                o_w[dt][i] *= inv_w;
            }
    }

    // ---- fusion epilogue (o_cmp from out, o_s & o_w in regs) ----
    float4 oc[8];
    #pragma unroll
    for (int dt = 0; dt < 8; ++dt)
        oc[dt] = *reinterpret_cast<const float4*>(out + th * 1024 + hh * 128 + dt * 16 + g * 4);
    const float* fwp = fw + hh * 3 * 384;
    float p0 = 0.f, p1 = 0.f, p2 = 0.f;
    #pragma unroll
    for (int dt = 0; dt < 8; ++dt) {
        #pragma unroll
        for (int i = 0; i < 4; ++i) {
            int d = dt * 16 + g * 4 + i;
            float a = (i == 0) ? oc[dt].x : (i == 1) ? oc[dt].y : (i == 2) ? oc[dt].z : oc[dt].w;
            float bsl = o_s[dt][i];
            float cw = o_w[dt][i];
            p0 += fwp[0 * 384 + d] * a + fwp[0 * 384 + 128 + d] * bsl + fwp[0 * 384 + 256 + d] * cw;
            p1 += fwp[1 * 384 + d] * a + fwp[1 * 384 + 128 + d] * bsl + fwp[1 * 384 + 256 + d] * cw;
            p2 += fwp[2 * 384 + d] * a + fwp[2 * 384 + 128 + d] * bsl + fwp[2 * 384 + 256 + d] * cw;
        }
    }
    p0 += __shfl_xor(p0, 16); p0 += __shfl_xor(p0, 32);
    p1 += __shfl_xor(p1, 16); p1 += __shfl_xor(p1, 32);
    p2 += __shfl_xor(p2, 16); p2 += __shfl_xor(p2, 32);
    float mx = fmaxf(p0, fmaxf(p1, p2));
    float e0 = expf(p0 - mx), e1 = expf(p1 - mx), e2 = expf(p2 - mx);
    float inv3 = 1.f / (e0 + e1 + e2);
    float w0 = e0 * inv3, w1 = e1 * inv3, w2 = e2 * inv3;
    #pragma unroll
    for (int dt = 0; dt < 8; ++dt) {
        float4 r;
        r.x = w0 * oc[dt].x + w1 * o_s[dt][0] + w2 * o_w[dt][0];
        r.y = w0 * oc[dt].y + w1 * o_s[dt][1] + w2 * o_w[dt][1];
        r.z = w0 * oc[dt].z + w1 * o_s[dt][2] + w2 * o_w[dt][2];
        r.w = w0 * oc[dt].w + w1 * o_s[dt][3] + w2 * o_w[dt][3];
        *reinterpret_cast<float4*>(out + th * 1024 + hh * 128 + dt * 16 + g * 4) = r;
    }
}

extern "C" void kernel_launch(void* const* d_in, const int* in_sizes, int n_in,
                              void* d_out, int out_size, void* d_ws, size_t ws_size,
                              hipStream_t stream) {
    (void)in_sizes; (void)n_in; (void)out_size; (void)ws_size;
    const float* q   = (const float*)d_in[0];
    const float* k   = (const float*)d_in[1];
    const float* v   = (const float*)d_in[2];
    const float* wk  = (const float*)d_in[3];
    const float* wvg = (const float*)d_in[4];
    const float* fw  = (const float*)d_in[5];
    float* out = (float*)d_out;
    float* ws = (float*)d_ws;
    float* ck = ws;
    float* cv = ws + NCMP * 128;
    unsigned int* selmask = (unsigned int*)(ws + 2 * NCMP * 128);
    unsigned short* kbf = (unsigned short*)(ws + 2 * NCMP * 128 + 2048);
    unsigned short* vtbf = kbf + 2048 * 128;

    k_convert<<<dim3(256), dim3(256), 0, stream>>>(k, v, kbf, vtbf);
    k_compress2<<<dim3(2 * NCMP), dim3(256), 0, stream>>>(k, v, wk, wvg, ck, cv);
    k_cmp_attn<<<dim3(2048 / TB), dim3(256), 0, stream>>>(q, ck, cv, out, selmask);
    k_main<<<dim3(1024), dim3(256), 0, stream>>>(q, kbf, vtbf, selmask, fw, out);
}

// Round 8
// 233.087 us; speedup vs baseline: 1.0352x; 1.0352x over previous
//
#include <hip/hip_runtime.h>

// NSA constants
#define NCMP 127
#define SCALE 0.08838834764831845f
#define QSCALE (0.08838834764831845f * 1.4426950408889634f)  // SCALE * log2(e)
#define TB 8    // t's per WG in k_cmp_attn

typedef __attribute__((ext_vector_type(8))) short bf16x8;
typedef __attribute__((ext_vector_type(4))) float f32x4;

__device__ __forceinline__ unsigned short f2bf(float x) {
    union { float f; unsigned u; } a; a.f = x;
    unsigned r = a.u + 0x7fffu + ((a.u >> 16) & 1u);
    return (unsigned short)(r >> 16);
}
__device__ __forceinline__ float dot4(float4 a, float4 b) {
    return a.x * b.x + a.y * b.y + a.z * b.z + a.w * b.w;
}

// ------------- Kernel A: fused k+v compress (gate-pooled blocks) -------------
__global__ __launch_bounds__(256) void k_compress2(const float* __restrict__ kk,
                                                   const float* __restrict__ vv,
                                                   const float* __restrict__ wk,
                                                   const float* __restrict__ wv,
                                                   float* __restrict__ ck,
                                                   float* __restrict__ cv) {
    __shared__ float blk[4096];   // 32 x 128 f32
    __shared__ float gate[32];
    int n = blockIdx.x >> 1;
    int which = blockIdx.x & 1;
    const float* src = which ? vv : kk;
    const float* w   = which ? wv : wk;
    float* out       = which ? cv : ck;
    int tid = threadIdx.x;

    {
        const float4* sp = reinterpret_cast<const float4*>(src + n * 16 * 128);
        float4* bp = reinterpret_cast<float4*>(blk);
        #pragma unroll
        for (int i = 0; i < 4; ++i) bp[tid + 256 * i] = sp[tid + 256 * i];
    }
    __syncthreads();

    {
        int j = tid >> 3, sub = tid & 7;
        const float4* wp = reinterpret_cast<const float4*>(w + j * 4096);
        const float4* bp = reinterpret_cast<const float4*>(blk);
        float s0 = 0.f, s1 = 0.f, s2 = 0.f, s3 = 0.f;
        for (int i = sub * 4; i < 1024; i += 32) {
            float4 w0 = wp[i], w1 = wp[i + 1], w2 = wp[i + 2], w3 = wp[i + 3];
            s0 += dot4(bp[i], w0);
            s1 += dot4(bp[i + 1], w1);
            s2 += dot4(bp[i + 2], w2);
            s3 += dot4(bp[i + 3], w3);
        }
        float s = (s0 + s1) + (s2 + s3);
        s += __shfl_xor(s, 1);
        s += __shfl_xor(s, 2);
        s += __shfl_xor(s, 4);
        if (sub == 0) gate[j] = s;
    }
    __syncthreads();

    if (tid < 32) {
        float gv = gate[tid];
        float m = gv;
        #pragma unroll
        for (int off = 16; off > 0; off >>= 1) m = fmaxf(m, __shfl_xor(m, off));
        float e = expf(gv - m);
        float ss = e;
        #pragma unroll
        for (int off = 16; off > 0; off >>= 1) ss += __shfl_xor(ss, off);
        gate[tid] = e / ss;
    }
    __syncthreads();

    if (tid < 128) {
        float acc = 0.f;
        #pragma unroll
        for (int kx = 0; kx < 32; ++kx) acc += gate[kx] * blk[kx * 128 + tid];
        out[n * 128 + tid] = acc;
    }
}

// ------------- Kernel D: f32 -> bf16 convert (K row-major, V transposed) -------------
__global__ __launch_bounds__(256) void k_convert(const float* __restrict__ k,
                                                 const float* __restrict__ v,
                                                 unsigned short* __restrict__ kbf,
                                                 unsigned short* __restrict__ vtbf) {
    int bid = blockIdx.x, tid = threadIdx.x;
    {
        int idx = bid * 1024 + tid * 4;
        float4 x = *reinterpret_cast<const float4*>(k + idx);
        unsigned short o[4] = {f2bf(x.x), f2bf(x.y), f2bf(x.z), f2bf(x.w)};
        *reinterpret_cast<ulonglong1*>(kbf + idx) = *reinterpret_cast<ulonglong1*>(o);
    }
    {
        int p = bid * 8 + (tid >> 5);
        int d4 = (tid & 31) << 2;
        float4 x = *reinterpret_cast<const float4*>(v + p * 128 + d4);
        vtbf[(d4 + 0) * 2048 + p] = f2bf(x.x);
        vtbf[(d4 + 1) * 2048 + p] = f2bf(x.y);
        vtbf[(d4 + 2) * 2048 + p] = f2bf(x.z);
        vtbf[(d4 + 3) * 2048 + p] = f2bf(x.w);
    }
}

// ---------- Kernel B: compressed attention + top-k block select ----------
__global__ __launch_bounds__(256) void k_cmp_attn(const float* __restrict__ q,
                                                  const float* __restrict__ ck,
                                                  const float* __restrict__ cv,
                                                  float* __restrict__ o_cmp,
                                                  unsigned int* __restrict__ selmask) {
    __shared__ float sc[64 * 132];
    __shared__ float pg[TB * 128];
    __shared__ float slc[TB * 32];
    __shared__ float adj[TB * 32];
    int t0 = blockIdx.x * TB;
    int tid = threadIdx.x;
    int wv = tid >> 6, ln = tid & 63;

    {
        int rh = wv >> 1, nh = wv & 1;
        int rg = ln >> 3, ds = ln & 7;
        int d0 = ds * 16;
        float4 qr[4][4];
        #pragma unroll
        for (int rr = 0; rr < 4; ++rr) {
            int r = rh * 32 + rg * 4 + rr;
            const float4* qp = reinterpret_cast<const float4*>(
                q + (t0 + (r >> 3)) * 1024 + (r & 7) * 128 + d0);
            #pragma unroll
            for (int cc = 0; cc < 4; ++cc) qr[rr][cc] = qp[cc];
        }
        for (int jn = 0; jn < 64; ++jn) {
            int n = nh * 64 + jn;
            if (n >= NCMP) break;
            const float4* kp = reinterpret_cast<const float4*>(ck + n * 128 + d0);
            float4 k0 = kp[0], k1 = kp[1], k2 = kp[2], k3 = kp[3];
            float part[4];
            #pragma unroll
            for (int rr = 0; rr < 4; ++rr)
                part[rr] = dot4(qr[rr][0], k0) + dot4(qr[rr][1], k1) +
                           dot4(qr[rr][2], k2) + dot4(qr[rr][3], k3);
            #pragma unroll
            for (int off = 1; off < 8; off <<= 1)
                #pragma unroll
                for (int rr = 0; rr < 4; ++rr) part[rr] += __shfl_xor(part[rr], off);
            if (ds == 0) {
                #pragma unroll
                for (int rr = 0; rr < 4; ++rr)
                    sc[(rh * 32 + rg * 4 + rr) * 132 + n] = part[rr] * SCALE;
            }
        }
    }
    __syncthreads();

    {
        int r = wv * 16 + (ln >> 2);
        int nl = ln & 3;
        int t = t0 + (r >> 3);
        int nvalid = (t >= 31) ? (((t - 31) >> 4) + 1) : 0;
        if (nvalid > NCMP) nvalid = NCMP;
        float* row = sc + r * 132;
        float m = -3e38f;
        for (int n = nl; n < nvalid; n += 4) m = fmaxf(m, row[n]);
        m = fmaxf(m, __shfl_xor(m, 1));
        m = fmaxf(m, __shfl_xor(m, 2));
        float ss = 0.f;
        for (int n = nl; n < 128; n += 4) {
            float e = (n < nvalid) ? expf(row[n] - m) : 0.f;
            ss += e;
            row[n] = e;
        }
        ss += __shfl_xor(ss, 1);
        ss += __shfl_xor(ss, 2);
        float inv = (ss > 0.f) ? 1.f / ss : 0.f;
        for (int n = nl; n < 128; n += 4) row[n] *= inv;
    }
    __syncthreads();

    {
        int rg = ln >> 3, ds = ln & 7, d0 = ds * 16;
        int rbase = wv * 16 + rg * 2;
        int nvmax = (t0 + 7 >= 31) ? (((t0 + 7 - 31) >> 4) + 1) : 0;
        if (nvmax > NCMP) nvmax = NCMP;
        float4 acc[2][4];
        #pragma unroll
        for (int rr = 0; rr < 2; ++rr)
            #pragma unroll
            for (int cc = 0; cc < 4; ++cc) acc[rr][cc] = (float4){0.f, 0.f, 0.f, 0.f};
        for (int n = 0; n < nvmax; ++n) {
            const float4* vp = reinterpret_cast<const float4*>(cv + n * 128 + d0);
            float4 v0 = vp[0], v1 = vp[1], v2 = vp[2], v3 = vp[3];
            #pragma unroll
            for (int rr = 0; rr < 2; ++rr) {
                float p = sc[(rbase + rr) * 132 + n];
                acc[rr][0].x += p * v0.x; acc[rr][0].y += p * v0.y; acc[rr][0].z += p * v0.z; acc[rr][0].w += p * v0.w;
                acc[rr][1].x += p * v1.x; acc[rr][1].y += p * v1.y; acc[rr][1].z += p * v1.z; acc[rr][1].w += p * v1.w;
                acc[rr][2].x += p * v2.x; acc[rr][2].y += p * v2.y; acc[rr][2].z += p * v2.z; acc[rr][2].w += p * v2.w;
                acc[rr][3].x += p * v3.x; acc[rr][3].y += p * v3.y; acc[rr][3].z += p * v3.z; acc[rr][3].w += p * v3.w;
            }
        }
        #pragma unroll
        for (int rr = 0; rr < 2; ++rr) {
            int r = rbase + rr;
            float4* op = reinterpret_cast<float4*>(
                o_cmp + (t0 + (r >> 3)) * 1024 + (r & 7) * 128 + d0);
            #pragma unroll
            for (int cc = 0; cc < 4; ++cc) op[cc] = acc[rr][cc];
        }
    }

    for (int i2 = tid; i2 < TB * 128; i2 += 256) {
        int tl = i2 >> 7, n = i2 & 127;
        float s = 0.f;
        #pragma unroll
        for (int h = 0; h < 8; ++h) s += sc[(tl * 8 + h) * 132 + n];
        pg[i2] = s;
    }
    __syncthreads();
    if (tid < TB * 32) {
        int tl = tid >> 5, s32 = tid & 31;
        float s = 0.f;
        #pragma unroll
        for (int j = 0; j < 4; ++j) {
            int n = s32 * 4 + j;
            if (n < NCMP) s += pg[tl * 128 + n];
        }
        slc[tid] = s;
    }
    __syncthreads();
    if (tid < TB) {
        int t = t0 + tid;
        int qblk = t >> 6;
        float* a = adj + tid * 32;
        for (int s = 0; s < 32; ++s) {
            if (s > qblk) a[s] = -1e30f;
            else a[s] = slc[tid * 32 + s] + ((s == 0 || s > qblk - 2) ? 1e30f : 0.f);
        }
        unsigned int msk = 0u;
        for (int it = 0; it < 16; ++it) {
            float best = -2e38f; int bi = 0;
            for (int s = 0; s < 32; ++s) { if (a[s] > best) { best = a[s]; bi = s; } }
            if (best <= -5e29f) break;
            msk |= 1u << bi;
            a[bi] = -2e38f;
        }
        selmask[t] = msk;
    }
}

// -------- Kernel C: branch-fused, 4-way split-K, CU-balanced swizzle --------
__global__ __launch_bounds__(256, 4) void k_main(const float* __restrict__ q,
                                              const unsigned short* __restrict__ kbf,
                                              const unsigned short* __restrict__ vtbf,
                                              const unsigned int* __restrict__ selmask,
                                              const float* __restrict__ fw,
                                              float* __restrict__ out) {
    __shared__ float mrg[4][16 * 132];             // 4 publish buffers (2 waves x 2 branches)
    __shared__ float mlbuf[4][2][16][2];           // wave, br, row, {m,l}

    // Anti-symmetric balance: CU r hosts bids {r, r+256, r+512, r+768}.
    // pair-sum per CU = r + (511-r) + (512+r) + (1023-r) = 2046 (constant).
    int bid = blockIdx.x;
    int jr = bid >> 8, rr_ = bid & 255;
    int pairidx = (jr << 8) | ((jr & 1) ? (255 - rr_) : rr_);
    int tp = pairidx * 2;

    int tid = threadIdx.x;
    int wv = tid >> 6, ln = tid & 63;
    int c = ln & 15, g = ln >> 4;

    unsigned int sm0 = selmask[tp], sm1 = selmask[tp + 1];
    unsigned int sm_wave = sm0 | sm1;

    // per-lane q-row: row = c -> t = tp + (c>>3), h = c&7
    int th = tp + (c >> 3);
    int hh = c & 7;
    unsigned int smc = (c >> 3) ? sm1 : sm0;

    // Q fragments (B-operand for swapped QK), pre-scaled to log2 domain
    bf16x8 qf[4];
    {
        const float* qp = q + th * 1024 + hh * 128;
        #pragma unroll
        for (int ks = 0; ks < 4; ++ks) {
            int d0 = ks * 32 + g * 8;
            float4 x = *reinterpret_cast<const float4*>(qp + d0);
            float4 y = *reinterpret_cast<const float4*>(qp + d0 + 4);
            bf16x8 f;
            f[0]=(short)f2bf(x.x*QSCALE); f[1]=(short)f2bf(x.y*QSCALE); f[2]=(short)f2bf(x.z*QSCALE); f[3]=(short)f2bf(x.w*QSCALE);
            f[4]=(short)f2bf(y.x*QSCALE); f[5]=(short)f2bf(y.y*QSCALE); f[6]=(short)f2bf(y.z*QSCALE); f[7]=(short)f2bf(y.w*QSCALE);
            qf[ks] = f;
        }
    }

    float m_s = -1e30f, l_s = 0.f, m_w = -1e30f, l_w = 0.f;
    f32x4 o_s[8], o_w[8];
    #pragma unroll
    for (int dt = 0; dt < 8; ++dt) {
        o_s[dt] = (f32x4){0.f, 0.f, 0.f, 0.f};
        o_w[dt] = (f32x4){0.f, 0.f, 0.f, 0.f};
    }

    int qblk_max = (tp + 1) >> 6;
    int wlo = (tp >= 575) ? (((tp - 575) >> 6) + 1) : 0;
    unsigned int all = (qblk_max >= 31) ? 0xFFFFFFFFu : ((1u << (qblk_max + 1)) - 1u);
    unsigned int wmask = all & ~((1u << wlo) - 1u);
    unsigned int mm = (sm_wave & all) | wmask;     // union block list

    int srcA = ((g & 1) << 5) + c;
    int srcB = srcA + 16;
    bool hi = (g >= 2);

    int idx = 0;
    while (mm) {
        int b = __builtin_ctz(mm);
        mm &= mm - 1;
        if ((idx++ & 3) != wv) continue;

        bool s_act = (sm_wave >> b) & 1u;
        bool w_act = ((unsigned)(b * 64 + 575) > (unsigned)tp);
        bool selbit = (smc >> b) & 1u;

        // QK^T once per union block (swapped: S[qrow=c][pos])
        f32x4 sacc[4];
        #pragma unroll
        for (int nt = 0; nt < 4; ++nt) {
            f32x4 acc = (f32x4){0.f, 0.f, 0.f, 0.f};
            #pragma unroll
            for (int ks = 0; ks < 4; ++ks) {
                bf16x8 bfK = *reinterpret_cast<const bf16x8*>(
                    kbf + (b * 64 + nt * 16 + c) * 128 + ks * 32 + g * 8);
                acc = __builtin_amdgcn_mfma_f32_16x16x32_bf16(bfK, qf[ks], acc, 0, 0, 0);
            }
            sacc[nt] = acc;
        }

        unsigned int pw_s[8], pw_w[8];

        // ---- select softmax ----
        if (s_act) {
            float mloc = -1e30f;
            #pragma unroll
            for (int nt = 0; nt < 4; ++nt)
                #pragma unroll
                for (int i = 0; i < 4; ++i) {
                    int pos = b * 64 + nt * 16 + g * 4 + i;
                    bool val = selbit && (pos <= th);
                    float s = val ? sacc[nt][i] : -1e30f;
                    mloc = fmaxf(mloc, s);
                }
            mloc = fmaxf(mloc, __shfl_xor(mloc, 16));
            mloc = fmaxf(mloc, __shfl_xor(mloc, 32));
            float mn = fmaxf(m_s, mloc);
            float al = exp2f(m_s - mn);
            float lsum = 0.f;
            #pragma unroll
            for (int nt = 0; nt < 4; ++nt) {
                float pp[4];
                #pragma unroll
                for (int i = 0; i < 4; ++i) {
                    int pos = b * 64 + nt * 16 + g * 4 + i;
                    bool val = selbit && (pos <= th);
                    float p = val ? exp2f(sacc[nt][i] - mn) : 0.f;
                    pp[i] = p;
                    lsum += p;
                }
                asm("v_cvt_pk_bf16_f32 %0, %1, %2" : "=v"(pw_s[2*nt]) : "v"(pp[0]), "v"(pp[1]));
                asm("v_cvt_pk_bf16_f32 %0, %1, %2" : "=v"(pw_s[2*nt+1]) : "v"(pp[2]), "v"(pp[3]));
            }
            lsum += __shfl_xor(lsum, 16);
            lsum += __shfl_xor(lsum, 32);
            m_s = mn;
            l_s = l_s * al + lsum;
            if (__any(al != 1.f)) {
                #pragma unroll
                for (int dt = 0; dt < 8; ++dt)
                    #pragma unroll
                    for (int i = 0; i < 4; ++i)
                        o_s[dt][i] *= al;
            }
        }

        // ---- window softmax ----
        if (w_act) {
            float mloc = -1e30f;
            #pragma unroll
            for (int nt = 0; nt < 4; ++nt)
                #pragma unroll
                for (int i = 0; i < 4; ++i) {
                    int pos = b * 64 + nt * 16 + g * 4 + i;
                    bool val = (pos <= th) && (pos + 512 > th);
                    float s = val ? sacc[nt][i] : -1e30f;
                    mloc = fmaxf(mloc, s);
                }
            mloc = fmaxf(mloc, __shfl_xor(mloc, 16));
            mloc = fmaxf(mloc, __shfl_xor(mloc, 32));
            float mn = fmaxf(m_w, mloc);
            float al = exp2f(m_w - mn);
            float lsum = 0.f;
            #pragma unroll
            for (int nt = 0; nt < 4; ++nt) {
                float pp[4];
                #pragma unroll
                for (int i = 0; i < 4; ++i) {
                    int pos = b * 64 + nt * 16 + g * 4 + i;
                    bool val = (pos <= th) && (pos + 512 > th);
                    float p = val ? exp2f(sacc[nt][i] - mn) : 0.f;
                    pp[i] = p;
                    lsum += p;
                }
                asm("v_cvt_pk_bf16_f32 %0, %1, %2" : "=v"(pw_w[2*nt]) : "v"(pp[0]), "v"(pp[1]));
                asm("v_cvt_pk_bf16_f32 %0, %1, %2" : "=v"(pw_w[2*nt+1]) : "v"(pp[2]), "v"(pp[3]));
            }
            lsum += __shfl_xor(lsum, 16);
            lsum += __shfl_xor(lsum, 32);
            m_w = mn;
            l_w = l_w * al + lsum;
            if (__any(al != 1.f)) {
                #pragma unroll
                for (int dt = 0; dt < 8; ++dt)
                    #pragma unroll
                    for (int i = 0; i < 4; ++i)
                        o_w[dt][i] *= al;
            }
        }

        // ---- PV: V fragments loaded once, shared by both branches ----
        #pragma unroll
        for (int ks = 0; ks < 2; ++ks) {
            bf16x8 pa_s = {}, pa_w = {};
            if (s_act) {
                unsigned int a0 = __shfl(pw_s[4*ks+0], srcA);
                unsigned int a1 = __shfl(pw_s[4*ks+1], srcA);
                unsigned int a2 = __shfl(pw_s[4*ks+0], srcB);
                unsigned int a3 = __shfl(pw_s[4*ks+1], srcB);
                unsigned int b0 = __shfl(pw_s[4*ks+2], srcA);
                unsigned int b1 = __shfl(pw_s[4*ks+3], srcA);
                unsigned int b2 = __shfl(pw_s[4*ks+2], srcB);
                unsigned int b3 = __shfl(pw_s[4*ks+3], srcB);
                unsigned int wp[4] = {hi ? b0 : a0, hi ? b1 : a1, hi ? b2 : a2, hi ? b3 : a3};
                pa_s = *reinterpret_cast<bf16x8*>(wp);
            }
            if (w_act) {
                unsigned int a0 = __shfl(pw_w[4*ks+0], srcA);
                unsigned int a1 = __shfl(pw_w[4*ks+1], srcA);
                unsigned int a2 = __shfl(pw_w[4*ks+0], srcB);
                unsigned int a3 = __shfl(pw_w[4*ks+1], srcB);
                unsigned int b0 = __shfl(pw_w[4*ks+2], srcA);
                unsigned int b1 = __shfl(pw_w[4*ks+3], srcA);
                unsigned int b2 = __shfl(pw_w[4*ks+2], srcB);
                unsigned int b3 = __shfl(pw_w[4*ks+3], srcB);
                unsigned int wp[4] = {hi ? b0 : a0, hi ? b1 : a1, hi ? b2 : a2, hi ? b3 : a3};
                pa_w = *reinterpret_cast<bf16x8*>(wp);
            }
            #pragma unroll
            for (int dt = 0; dt < 8; ++dt) {
                bf16x8 bfV = *reinterpret_cast<const bf16x8*>(
                    vtbf + (dt * 16 + c) * 2048 + b * 64 + ks * 32 + g * 8);
                if (s_act) o_s[dt] = __builtin_amdgcn_mfma_f32_16x16x32_bf16(bfV, pa_s, o_s[dt], 0, 0, 0);
                if (w_act) o_w[dt] = __builtin_amdgcn_mfma_f32_16x16x32_bf16(bfV, pa_w, o_w[dt], 0, 0, 0);
            }
        }
    }

    // ---- merge: 2-step tree, both branches per publish ----
    if (g == 0) {
        mlbuf[wv][0][c][0] = m_s; mlbuf[wv][0][c][1] = l_s;
        mlbuf[wv][1][c][0] = m_w; mlbuf[wv][1][c][1] = l_w;
    }
    if (wv & 1) {
        int base = (wv >> 1) * 2;
        #pragma unroll
        for (int dt = 0; dt < 8; ++dt) {
            *reinterpret_cast<float4*>(&mrg[base][c * 132 + dt * 16 + g * 4]) =
                (float4){o_s[dt][0], o_s[dt][1], o_s[dt][2], o_s[dt][3]};
            *reinterpret_cast<float4*>(&mrg[base + 1][c * 132 + dt * 16 + g * 4]) =
                (float4){o_w[dt][0], o_w[dt][1], o_w[dt][2], o_w[dt][3]};
        }
    }
    __syncthreads();
    if (!(wv & 1)) {
        int base = (wv >> 1) * 2;
        {   // select
            float m1 = mlbuf[wv + 1][0][c][0], l1 = mlbuf[wv + 1][0][c][1];
            float mn = fmaxf(m_s, m1);
            float a0 = exp2f(m_s - mn), a1 = exp2f(m1 - mn);
            m_s = mn; l_s = a0 * l_s + a1 * l1;
            #pragma unroll
            for (int dt = 0; dt < 8; ++dt) {
                float4 o1 = *reinterpret_cast<const float4*>(&mrg[base][c * 132 + dt * 16 + g * 4]);
                o_s[dt][0] = a0 * o_s[dt][0] + a1 * o1.x;
                o_s[dt][1] = a0 * o_s[dt][1] + a1 * o1.y;
                o_s[dt][2] = a0 * o_s[dt][2] + a1 * o1.z;
                o_s[dt][3] = a0 * o_s[dt][3] + a1 * o1.w;
            }
        }
        {   // window
            float m1 = mlbuf[wv + 1][1][c][0], l1 = mlbuf[wv + 1][1][c][1];
            float mn = fmaxf(m_w, m1);
            float a0 = exp2f(m_w - mn), a1 = exp2f(m1 - mn);
            m_w = mn; l_w = a0 * l_w + a1 * l1;
            #pragma unroll
            for (int dt = 0; dt < 8; ++dt) {
                float4 o1 = *reinterpret_cast<const float4*>(&mrg[base + 1][c * 132 + dt * 16 + g * 4]);
                o_w[dt][0] = a0 * o_w[dt][0] + a1 * o1.x;
                o_w[dt][1] = a0 * o_w[dt][1] + a1 * o1.y;
                o_w[dt][2] = a0 * o_w[dt][2] + a1 * o1.z;
                o_w[dt][3] = a0 * o_w[dt][3] + a1 * o1.w;
            }
        }
    }
    __syncthreads();
    if (wv == 2) {
        if (g == 0) {
            mlbuf[2][0][c][0] = m_s; mlbuf[2][0][c][1] = l_s;
            mlbuf[2][1][c][0] = m_w; mlbuf[2][1][c][1] = l_w;
        }
        #pragma unroll
        for (int dt = 0; dt < 8; ++dt) {
            *reinterpret_cast<float4*>(&mrg[0][c * 132 + dt * 16 + g * 4]) =
                (float4){o_s[dt][0], o_s[dt][1], o_s[dt][2], o_s[dt][3]};
            *reinterpret_cast<float4*>(&mrg[1][c * 132 + dt * 16 + g * 4]) =
                (float4){o_w[dt][0], o_w[dt][1], o_w[dt][2], o_w[dt][3]};
        }
    }
    __syncthreads();
    if (wv != 0) return;

    {   // final merge of waves {2,3} into wave 0 — select
        float m1 = mlbuf[2][0][c][0], l1 = mlbuf[2][0][c][1];
        float mn = fmaxf(m_s, m1);
        float a0 = exp2f(m_s - mn), a1 = exp2f(m1 - mn);
        l_s = a0 * l_s + a1 * l1;
        #pragma unroll
        for (int dt = 0; dt < 8; ++dt) {
            float4 o1 = *reinterpret_cast<const float4*>(&mrg[0][c * 132 + dt * 16 + g * 4]);
            o_s[dt][0] = a0 * o_s[dt][0] + a1 * o1.x;
            o_s[dt][1] = a0 * o_s[dt][1] + a1 * o1.y;
            o_s[dt][2] = a0 * o_s[dt][2] + a1 * o1.z;
            o_s[dt][3] = a0 * o_s[dt][3] + a1 * o1.w;
        }
    }
    {   // window
        float m1 = mlbuf[2][1][c][0], l1 = mlbuf[2][1][c][1];
        float mn = fmaxf(m_w, m1);
        float a0 = exp2f(m_w - mn), a1 = exp2f(m1 - mn);
        l_w = a0 * l_w + a1 * l1;
        #pragma unroll
        for (int dt = 0; dt < 8; ++dt) {
            float4 o1 = *reinterpret_cast<const float4*>(&mrg[1][c * 132 + dt * 16 + g * 4]);
            o_w[dt][0] = a0 * o_w[dt][0] + a1 * o1.x;
            o_w[dt][1] = a0 * o_w[dt][1] + a1 * o1.y;
            o_w[dt][2] = a0 * o_w[dt][2] + a1 * o1.z;
            o_w[dt][3] = a0 * o_w[dt][3] + a1 * o1.w;
        }
    }
    // normalize both branches
    {
        float inv_s = 1.f / l_s, inv_w = 1.f / l_w;
        #pragma unroll
        for (int dt = 0; dt < 8; ++dt)
            #pragma unroll
            for (int i = 0; i < 4; ++i) {
                o_s[dt][i] *= inv_s;
                o_w[dt][i] *= inv_w;
            }
    }

    // ---- fusion epilogue (o_cmp from out, o_s & o_w in regs) ----
    float4 oc[8];
    #pragma unroll
    for (int dt = 0; dt < 8; ++dt)
        oc[dt] = *reinterpret_cast<const float4*>(out + th * 1024 + hh * 128 + dt * 16 + g * 4);
    const float* fwp = fw + hh * 3 * 384;
    float p0 = 0.f, p1 = 0.f, p2 = 0.f;
    #pragma unroll
    for (int dt = 0; dt < 8; ++dt) {
        #pragma unroll
        for (int i = 0; i < 4; ++i) {
            int d = dt * 16 + g * 4 + i;
            float a = (i == 0) ? oc[dt].x : (i == 1) ? oc[dt].y : (i == 2) ? oc[dt].z : oc[dt].w;
            float bsl = o_s[dt][i];
            float cw = o_w[dt][i];
            p0 += fwp[0 * 384 + d] * a + fwp[0 * 384 + 128 + d] * bsl + fwp[0 * 384 + 256 + d] * cw;
            p1 += fwp[1 * 384 + d] * a + fwp[1 * 384 + 128 + d] * bsl + fwp[1 * 384 + 256 + d] * cw;
            p2 += fwp[2 * 384 + d] * a + fwp[2 * 384 + 128 + d] * bsl + fwp[2 * 384 + 256 + d] * cw;
        }
    }
    p0 += __shfl_xor(p0, 16); p0 += __shfl_xor(p0, 32);
    p1 += __shfl_xor(p1, 16); p1 += __shfl_xor(p1, 32);
    p2 += __shfl_xor(p2, 16); p2 += __shfl_xor(p2, 32);
    float mx = fmaxf(p0, fmaxf(p1, p2));
    float e0 = expf(p0 - mx), e1 = expf(p1 - mx), e2 = expf(p2 - mx);
    float inv3 = 1.f / (e0 + e1 + e2);
    float w0 = e0 * inv3, w1 = e1 * inv3, w2 = e2 * inv3;
    #pragma unroll
    for (int dt = 0; dt < 8; ++dt) {
        float4 r;
        r.x = w0 * oc[dt].x + w1 * o_s[dt][0] + w2 * o_w[dt][0];
        r.y = w0 * oc[dt].y + w1 * o_s[dt][1] + w2 * o_w[dt][1];
        r.z = w0 * oc[dt].z + w1 * o_s[dt][2] + w2 * o_w[dt][2];
        r.w = w0 * oc[dt].w + w1 * o_s[dt][3] + w2 * o_w[dt][3];
        *reinterpret_cast<float4*>(out + th * 1024 + hh * 128 + dt * 16 + g * 4) = r;
    }
}

extern "C" void kernel_launch(void* const* d_in, const int* in_sizes, int n_in,
                              void* d_out, int out_size, void* d_ws, size_t ws_size,
                              hipStream_t stream) {
    (void)in_sizes; (void)n_in; (void)out_size; (void)ws_size;
    const float* q   = (const float*)d_in[0];
    const float* k   = (const float*)d_in[1];
    const float* v   = (const float*)d_in[2];
    const float* wk  = (const float*)d_in[3];
    const float* wvg = (const float*)d_in[4];
    const float* fw  = (const float*)d_in[5];
    float* out = (float*)d_out;
    float* ws = (float*)d_ws;
    float* ck = ws;
    float* cv = ws + NCMP * 128;
    unsigned int* selmask = (unsigned int*)(ws + 2 * NCMP * 128);
    unsigned short* kbf = (unsigned short*)(ws + 2 * NCMP * 128 + 2048);
    unsigned short* vtbf = kbf + 2048 * 128;

    k_convert<<<dim3(256), dim3(256), 0, stream>>>(k, v, kbf, vtbf);
    k_compress2<<<dim3(2 * NCMP), dim3(256), 0, stream>>>(k, v, wk, wvg, ck, cv);
    k_cmp_attn<<<dim3(2048 / TB), dim3(256), 0, stream>>>(q, ck, cv, out, selmask);
    k_main<<<dim3(1024), dim3(256), 0, stream>>>(q, kbf, vtbf, selmask, fw, out);
}

// Round 9
// 212.359 us; speedup vs baseline: 1.1363x; 1.0976x over previous
//
#include <hip/hip_runtime.h>

// NSA constants
#define NCMP 127
#define SCALE 0.08838834764831845f
#define QSCALE (0.08838834764831845f * 1.4426950408889634f)  // SCALE * log2(e)
#define TB 8    // t's per WG in k_cmp_attn

typedef __attribute__((ext_vector_type(8))) short bf16x8;
typedef __attribute__((ext_vector_type(4))) float f32x4;

__device__ __forceinline__ unsigned short f2bf(float x) {
    union { float f; unsigned u; } a; a.f = x;
    unsigned r = a.u + 0x7fffu + ((a.u >> 16) & 1u);
    return (unsigned short)(r >> 16);
}
__device__ __forceinline__ float dot4(float4 a, float4 b) {
    return a.x * b.x + a.y * b.y + a.z * b.z + a.w * b.w;
}

// ------------- Kernel A: fused k+v compress (gate-pooled blocks) -------------
__global__ __launch_bounds__(256) void k_compress2(const float* __restrict__ kk,
                                                   const float* __restrict__ vv,
                                                   const float* __restrict__ wk,
                                                   const float* __restrict__ wv,
                                                   float* __restrict__ ck,
                                                   float* __restrict__ cv) {
    __shared__ float blk[4096];   // 32 x 128 f32
    __shared__ float gate[32];
    int n = blockIdx.x >> 1;
    int which = blockIdx.x & 1;
    const float* src = which ? vv : kk;
    const float* w   = which ? wv : wk;
    float* out       = which ? cv : ck;
    int tid = threadIdx.x;

    {
        const float4* sp = reinterpret_cast<const float4*>(src + n * 16 * 128);
        float4* bp = reinterpret_cast<float4*>(blk);
        #pragma unroll
        for (int i = 0; i < 4; ++i) bp[tid + 256 * i] = sp[tid + 256 * i];
    }
    __syncthreads();

    {
        int j = tid >> 3, sub = tid & 7;
        const float4* wp = reinterpret_cast<const float4*>(w + j * 4096);
        const float4* bp = reinterpret_cast<const float4*>(blk);
        float s0 = 0.f, s1 = 0.f, s2 = 0.f, s3 = 0.f;
        for (int i = sub * 4; i < 1024; i += 32) {
            float4 w0 = wp[i], w1 = wp[i + 1], w2 = wp[i + 2], w3 = wp[i + 3];
            s0 += dot4(bp[i], w0);
            s1 += dot4(bp[i + 1], w1);
            s2 += dot4(bp[i + 2], w2);
            s3 += dot4(bp[i + 3], w3);
        }
        float s = (s0 + s1) + (s2 + s3);
        s += __shfl_xor(s, 1);
        s += __shfl_xor(s, 2);
        s += __shfl_xor(s, 4);
        if (sub == 0) gate[j] = s;
    }
    __syncthreads();

    if (tid < 32) {
        float gv = gate[tid];
        float m = gv;
        #pragma unroll
        for (int off = 16; off > 0; off >>= 1) m = fmaxf(m, __shfl_xor(m, off));
        float e = expf(gv - m);
        float ss = e;
        #pragma unroll
        for (int off = 16; off > 0; off >>= 1) ss += __shfl_xor(ss, off);
        gate[tid] = e / ss;
    }
    __syncthreads();

    if (tid < 128) {
        float acc = 0.f;
        #pragma unroll
        for (int kx = 0; kx < 32; ++kx) acc += gate[kx] * blk[kx * 128 + tid];
        out[n * 128 + tid] = acc;
    }
}

// ------------- Kernel D: f32 -> bf16 convert (K row-major, V transposed) -------------
__global__ __launch_bounds__(256) void k_convert(const float* __restrict__ k,
                                                 const float* __restrict__ v,
                                                 unsigned short* __restrict__ kbf,
                                                 unsigned short* __restrict__ vtbf) {
    int bid = blockIdx.x, tid = threadIdx.x;
    {
        int idx = bid * 1024 + tid * 4;
        float4 x = *reinterpret_cast<const float4*>(k + idx);
        unsigned short o[4] = {f2bf(x.x), f2bf(x.y), f2bf(x.z), f2bf(x.w)};
        *reinterpret_cast<ulonglong1*>(kbf + idx) = *reinterpret_cast<ulonglong1*>(o);
    }
    {
        int p = bid * 8 + (tid >> 5);
        int d4 = (tid & 31) << 2;
        float4 x = *reinterpret_cast<const float4*>(v + p * 128 + d4);
        vtbf[(d4 + 0) * 2048 + p] = f2bf(x.x);
        vtbf[(d4 + 1) * 2048 + p] = f2bf(x.y);
        vtbf[(d4 + 2) * 2048 + p] = f2bf(x.z);
        vtbf[(d4 + 3) * 2048 + p] = f2bf(x.w);
    }
}

// ---------- Kernel B: compressed attention + top-k block select ----------
__global__ __launch_bounds__(256) void k_cmp_attn(const float* __restrict__ q,
                                                  const float* __restrict__ ck,
                                                  const float* __restrict__ cv,
                                                  float* __restrict__ o_cmp,
                                                  unsigned int* __restrict__ selmask) {
    __shared__ float sc[64 * 132];
    __shared__ float pg[TB * 128];
    __shared__ float slc[TB * 32];
    __shared__ float adj[TB * 32];
    int t0 = blockIdx.x * TB;
    int tid = threadIdx.x;
    int wv = tid >> 6, ln = tid & 63;

    {
        int rh = wv >> 1, nh = wv & 1;
        int rg = ln >> 3, ds = ln & 7;
        int d0 = ds * 16;
        float4 qr[4][4];
        #pragma unroll
        for (int rr = 0; rr < 4; ++rr) {
            int r = rh * 32 + rg * 4 + rr;
            const float4* qp = reinterpret_cast<const float4*>(
                q + (t0 + (r >> 3)) * 1024 + (r & 7) * 128 + d0);
            #pragma unroll
            for (int cc = 0; cc < 4; ++cc) qr[rr][cc] = qp[cc];
        }
        for (int jn = 0; jn < 64; ++jn) {
            int n = nh * 64 + jn;
            if (n >= NCMP) break;
            const float4* kp = reinterpret_cast<const float4*>(ck + n * 128 + d0);
            float4 k0 = kp[0], k1 = kp[1], k2 = kp[2], k3 = kp[3];
            float part[4];
            #pragma unroll
            for (int rr = 0; rr < 4; ++rr)
                part[rr] = dot4(qr[rr][0], k0) + dot4(qr[rr][1], k1) +
                           dot4(qr[rr][2], k2) + dot4(qr[rr][3], k3);
            #pragma unroll
            for (int off = 1; off < 8; off <<= 1)
                #pragma unroll
                for (int rr = 0; rr < 4; ++rr) part[rr] += __shfl_xor(part[rr], off);
            if (ds == 0) {
                #pragma unroll
                for (int rr = 0; rr < 4; ++rr)
                    sc[(rh * 32 + rg * 4 + rr) * 132 + n] = part[rr] * SCALE;
            }
        }
    }
    __syncthreads();

    {
        int r = wv * 16 + (ln >> 2);
        int nl = ln & 3;
        int t = t0 + (r >> 3);
        int nvalid = (t >= 31) ? (((t - 31) >> 4) + 1) : 0;
        if (nvalid > NCMP) nvalid = NCMP;
        float* row = sc + r * 132;
        float m = -3e38f;
        for (int n = nl; n < nvalid; n += 4) m = fmaxf(m, row[n]);
        m = fmaxf(m, __shfl_xor(m, 1));
        m = fmaxf(m, __shfl_xor(m, 2));
        float ss = 0.f;
        for (int n = nl; n < 128; n += 4) {
            float e = (n < nvalid) ? expf(row[n] - m) : 0.f;
            ss += e;
            row[n] = e;
        }
        ss += __shfl_xor(ss, 1);
        ss += __shfl_xor(ss, 2);
        float inv = (ss > 0.f) ? 1.f / ss : 0.f;
        for (int n = nl; n < 128; n += 4) row[n] *= inv;
    }
    __syncthreads();

    {
        int rg = ln >> 3, ds = ln & 7, d0 = ds * 16;
        int rbase = wv * 16 + rg * 2;
        int nvmax = (t0 + 7 >= 31) ? (((t0 + 7 - 31) >> 4) + 1) : 0;
        if (nvmax > NCMP) nvmax = NCMP;
        float4 acc[2][4];
        #pragma unroll
        for (int rr = 0; rr < 2; ++rr)
            #pragma unroll
            for (int cc = 0; cc < 4; ++cc) acc[rr][cc] = (float4){0.f, 0.f, 0.f, 0.f};
        for (int n = 0; n < nvmax; ++n) {
            const float4* vp = reinterpret_cast<const float4*>(cv + n * 128 + d0);
            float4 v0 = vp[0], v1 = vp[1], v2 = vp[2], v3 = vp[3];
            #pragma unroll
            for (int rr = 0; rr < 2; ++rr) {
                float p = sc[(rbase + rr) * 132 + n];
                acc[rr][0].x += p * v0.x; acc[rr][0].y += p * v0.y; acc[rr][0].z += p * v0.z; acc[rr][0].w += p * v0.w;
                acc[rr][1].x += p * v1.x; acc[rr][1].y += p * v1.y; acc[rr][1].z += p * v1.z; acc[rr][1].w += p * v1.w;
                acc[rr][2].x += p * v2.x; acc[rr][2].y += p * v2.y; acc[rr][2].z += p * v2.z; acc[rr][2].w += p * v2.w;
                acc[rr][3].x += p * v3.x; acc[rr][3].y += p * v3.y; acc[rr][3].z += p * v3.z; acc[rr][3].w += p * v3.w;
            }
        }
        #pragma unroll
        for (int rr = 0; rr < 2; ++rr) {
            int r = rbase + rr;
            float4* op = reinterpret_cast<float4*>(
                o_cmp + (t0 + (r >> 3)) * 1024 + (r & 7) * 128 + d0);
            #pragma unroll
            for (int cc = 0; cc < 4; ++cc) op[cc] = acc[rr][cc];
        }
    }

    for (int i2 = tid; i2 < TB * 128; i2 += 256) {
        int tl = i2 >> 7, n = i2 & 127;
        float s = 0.f;
        #pragma unroll
        for (int h = 0; h < 8; ++h) s += sc[(tl * 8 + h) * 132 + n];
        pg[i2] = s;
    }
    __syncthreads();
    if (tid < TB * 32) {
        int tl = tid >> 5, s32 = tid & 31;
        float s = 0.f;
        #pragma unroll
        for (int j = 0; j < 4; ++j) {
            int n = s32 * 4 + j;
            if (n < NCMP) s += pg[tl * 128 + n];
        }
        slc[tid] = s;
    }
    __syncthreads();
    if (tid < TB) {
        int t = t0 + tid;
        int qblk = t >> 6;
        float* a = adj + tid * 32;
        for (int s = 0; s < 32; ++s) {
            if (s > qblk) a[s] = -1e30f;
            else a[s] = slc[tid * 32 + s] + ((s == 0 || s > qblk - 2) ? 1e30f : 0.f);
        }
        unsigned int msk = 0u;
        for (int it = 0; it < 16; ++it) {
            float best = -2e38f; int bi = 0;
            for (int s = 0; s < 32; ++s) { if (a[s] > best) { best = a[s]; bi = s; } }
            if (best <= -5e29f) break;
            msk |= 1u << bi;
            a[bi] = -2e38f;
        }
        selmask[t] = msk;
    }
}

// -------- Kernel C: single-branch waves, batched-MLP passes, balanced swizzle --------
__global__ __launch_bounds__(256, 2) void k_main(const float* __restrict__ q,
                                              const unsigned short* __restrict__ kbf,
                                              const unsigned short* __restrict__ vtbf,
                                              const unsigned int* __restrict__ selmask,
                                              const float* __restrict__ fw,
                                              float* __restrict__ out) {
    __shared__ float mrg[2][16 * 132];             // per-branch merge buffers
    __shared__ float mlbuf[4][16][2];              // wave, row, {m,l}

    // Anti-symmetric balance: CU r hosts bids {r, r+256, r+512, r+768};
    // pair-sum per CU = 2046 (constant).
    int bid = blockIdx.x;
    int jr = bid >> 8, rr_ = bid & 255;
    int pairidx = (jr << 8) | ((jr & 1) ? (255 - rr_) : rr_);
    int tp = pairidx * 2;

    int tid = threadIdx.x;
    int wv = tid >> 6, ln = tid & 63;
    int c = ln & 15, g = ln >> 4;
    bool is_sel = (wv < 2);
    int w = wv & 1;              // split-K parity within branch

    unsigned int sm0 = selmask[tp], sm1 = selmask[tp + 1];
    unsigned int sm_wave = sm0 | sm1;

    // per-lane q-row: row = c -> t = tp + (c>>3), h = c&7
    int th = tp + (c >> 3);
    int hh = c & 7;
    unsigned int smc = (c >> 3) ? sm1 : sm0;

    // Q fragments (B-operand for swapped QK), pre-scaled to log2 domain
    bf16x8 qf[4];
    {
        const float* qp = q + th * 1024 + hh * 128;
        #pragma unroll
        for (int ks = 0; ks < 4; ++ks) {
            int d0 = ks * 32 + g * 8;
            float4 x = *reinterpret_cast<const float4*>(qp + d0);
            float4 y = *reinterpret_cast<const float4*>(qp + d0 + 4);
            bf16x8 f;
            f[0]=(short)f2bf(x.x*QSCALE); f[1]=(short)f2bf(x.y*QSCALE); f[2]=(short)f2bf(x.z*QSCALE); f[3]=(short)f2bf(x.w*QSCALE);
            f[4]=(short)f2bf(y.x*QSCALE); f[5]=(short)f2bf(y.y*QSCALE); f[6]=(short)f2bf(y.z*QSCALE); f[7]=(short)f2bf(y.w*QSCALE);
            qf[ks] = f;
        }
    }

    float m_run = -1e30f, l_run = 0.f;
    f32x4 o_acc[8];
    #pragma unroll
    for (int dt = 0; dt < 8; ++dt) o_acc[dt] = (f32x4){0.f, 0.f, 0.f, 0.f};

    int qblk_max = (tp + 1) >> 6;
    int srcA = ((g & 1) << 5) + c;
    int srcB = srcA + 16;
    bool hi = (g >= 2);

    auto process = [&](int b) {
        const unsigned short* kb = kbf + b * 64 * 128;
        const unsigned short* vb = vtbf + b * 64;

        // ---- batch ALL 16 K-fragment loads (one drain, full MLP) ----
        bf16x8 kf[4][4];
        #pragma unroll
        for (int nt = 0; nt < 4; ++nt)
            #pragma unroll
            for (int ks = 0; ks < 4; ++ks)
                kf[nt][ks] = *reinterpret_cast<const bf16x8*>(
                    kb + (nt * 16 + c) * 128 + ks * 32 + g * 8);

        // QK^T swapped: S[qrow=c][pos = b*64 + nt*16 + g*4 + i]
        f32x4 sacc[4];
        #pragma unroll
        for (int nt = 0; nt < 4; ++nt) {
            f32x4 acc = (f32x4){0.f, 0.f, 0.f, 0.f};
            #pragma unroll
            for (int ks = 0; ks < 4; ++ks)
                acc = __builtin_amdgcn_mfma_f32_16x16x32_bf16(kf[nt][ks], qf[ks], acc, 0, 0, 0);
            sacc[nt] = acc;
        }

        // ---- issue ALL 16 V loads now; latency hides under softmax+shuffles ----
        bf16x8 vf[2][8];
        #pragma unroll
        for (int ks = 0; ks < 2; ++ks)
            #pragma unroll
            for (int dt = 0; dt < 8; ++dt)
                vf[ks][dt] = *reinterpret_cast<const bf16x8*>(
                    vb + (dt * 16 + c) * 2048 + ks * 32 + g * 8);

        // mask + in-lane max (one q-row per lane)
        bool selbit = (smc >> b) & 1u;
        float mloc = -1e30f;
        #pragma unroll
        for (int nt = 0; nt < 4; ++nt) {
            #pragma unroll
            for (int i = 0; i < 4; ++i) {
                int pos = b * 64 + nt * 16 + g * 4 + i;
                bool val;
                if (is_sel) val = selbit && (pos <= th);
                else        val = (pos <= th) && (pos + 512 > th);
                float s = val ? sacc[nt][i] : -1e30f;
                sacc[nt][i] = s;
                mloc = fmaxf(mloc, s);
            }
        }
        mloc = fmaxf(mloc, __shfl_xor(mloc, 16));
        mloc = fmaxf(mloc, __shfl_xor(mloc, 32));
        float mn = fmaxf(m_run, mloc);
        float al = exp2f(m_run - mn);

        float lsum = 0.f;
        #pragma unroll
        for (int nt = 0; nt < 4; ++nt) {
            #pragma unroll
            for (int i = 0; i < 4; ++i) {
                float s = sacc[nt][i];
                float p = (s > -5e29f) ? exp2f(s - mn) : 0.f;
                sacc[nt][i] = p;
                lsum += p;
            }
        }
        lsum += __shfl_xor(lsum, 16);
        lsum += __shfl_xor(lsum, 32);
        m_run = mn;
        l_run = l_run * al + lsum;

        if (__any(al != 1.f)) {
            #pragma unroll
            for (int dt = 0; dt < 8; ++dt)
                #pragma unroll
                for (int i = 0; i < 4; ++i)
                    o_acc[dt][i] *= al;
        }

        // pack P rows to bf16 pairs
        unsigned int pw[8];
        #pragma unroll
        for (int nt = 0; nt < 4; ++nt) {
            unsigned int w0, w1;
            asm("v_cvt_pk_bf16_f32 %0, %1, %2" : "=v"(w0) : "v"(sacc[nt][0]), "v"(sacc[nt][1]));
            asm("v_cvt_pk_bf16_f32 %0, %1, %2" : "=v"(w1) : "v"(sacc[nt][2]), "v"(sacc[nt][3]));
            pw[2 * nt] = w0;
            pw[2 * nt + 1] = w1;
        }

        // in-register P^T B-frag assembly + PV (V already in regs)
        #pragma unroll
        for (int ks = 0; ks < 2; ++ks) {
            unsigned int a0 = __shfl(pw[4 * ks + 0], srcA);
            unsigned int a1 = __shfl(pw[4 * ks + 1], srcA);
            unsigned int a2 = __shfl(pw[4 * ks + 0], srcB);
            unsigned int a3 = __shfl(pw[4 * ks + 1], srcB);
            unsigned int b0 = __shfl(pw[4 * ks + 2], srcA);
            unsigned int b1 = __shfl(pw[4 * ks + 3], srcA);
            unsigned int b2 = __shfl(pw[4 * ks + 2], srcB);
            unsigned int b3 = __shfl(pw[4 * ks + 3], srcB);
            unsigned int wparr[4] = {hi ? b0 : a0, hi ? b1 : a1, hi ? b2 : a2, hi ? b3 : a3};
            bf16x8 pa = *reinterpret_cast<bf16x8*>(wparr);
            #pragma unroll
            for (int dt = 0; dt < 8; ++dt)
                o_acc[dt] = __builtin_amdgcn_mfma_f32_16x16x32_bf16(vf[ks][dt], pa, o_acc[dt], 0, 0, 0);
        }
    };

    if (is_sel) {
        unsigned int mm = sm_wave;
        if (qblk_max < 31) mm &= (1u << (qblk_max + 1)) - 1u;
        int idx = 0;
        while (mm) {
            int b = __builtin_ctz(mm);
            mm &= mm - 1;
            if ((idx++ & 1) == w) process(b);
        }
    } else {
        int wlo = (tp >= 575) ? (((tp - 575) >> 6) + 1) : 0;
        for (int b = wlo + w; b <= qblk_max; b += 2) process(b);
    }

    // ---- merge: wave1 -> wave0 (select), wave3 -> wave2 (window) ----
    if (w == 1) {
        if (g == 0) { mlbuf[wv][c][0] = m_run; mlbuf[wv][c][1] = l_run; }
        #pragma unroll
        for (int dt = 0; dt < 8; ++dt)
            *reinterpret_cast<float4*>(&mrg[wv >> 1][c * 132 + dt * 16 + g * 4]) =
                (float4){o_acc[dt][0], o_acc[dt][1], o_acc[dt][2], o_acc[dt][3]};
    }
    __syncthreads();
    if (w == 0) {
        float m1 = mlbuf[wv + 1][c][0];
        float l1 = mlbuf[wv + 1][c][1];
        float mn = fmaxf(m_run, m1);
        float a0 = exp2f(m_run - mn), a1 = exp2f(m1 - mn);
        l_run = a0 * l_run + a1 * l1;
        float inv = 1.f / l_run;
        #pragma unroll
        for (int dt = 0; dt < 8; ++dt) {
            float4 o1 = *reinterpret_cast<const float4*>(&mrg[wv >> 1][c * 132 + dt * 16 + g * 4]);
            o_acc[dt][0] = (a0 * o_acc[dt][0] + a1 * o1.x) * inv;
            o_acc[dt][1] = (a0 * o_acc[dt][1] + a1 * o1.y) * inv;
            o_acc[dt][2] = (a0 * o_acc[dt][2] + a1 * o1.z) * inv;
            o_acc[dt][3] = (a0 * o_acc[dt][3] + a1 * o1.w) * inv;
        }
    }
    // wave 2 publishes final (normalized) o_sw
    if (wv == 2) {
        #pragma unroll
        for (int dt = 0; dt < 8; ++dt)
            *reinterpret_cast<float4*>(&mrg[1][c * 132 + dt * 16 + g * 4]) =
                (float4){o_acc[dt][0], o_acc[dt][1], o_acc[dt][2], o_acc[dt][3]};
    }
    __syncthreads();
    if (wv != 0) return;

    // ---- fusion epilogue (wave 0: o_sel in regs, o_sw in mrg[1], o_cmp in out) ----
    float4 oc[8], ow[8];
    #pragma unroll
    for (int dt = 0; dt < 8; ++dt) {
        oc[dt] = *reinterpret_cast<const float4*>(out + th * 1024 + hh * 128 + dt * 16 + g * 4);
        ow[dt] = *reinterpret_cast<const float4*>(&mrg[1][c * 132 + dt * 16 + g * 4]);
    }
    const float* fwp = fw + hh * 3 * 384;
    float p0 = 0.f, p1 = 0.f, p2 = 0.f;
    #pragma unroll
    for (int dt = 0; dt < 8; ++dt) {
        #pragma unroll
        for (int i = 0; i < 4; ++i) {
            int d = dt * 16 + g * 4 + i;
            float a = (i == 0) ? oc[dt].x : (i == 1) ? oc[dt].y : (i == 2) ? oc[dt].z : oc[dt].w;
            float bsl = o_acc[dt][i];
            float cw = (i == 0) ? ow[dt].x : (i == 1) ? ow[dt].y : (i == 2) ? ow[dt].z : ow[dt].w;
            p0 += fwp[0 * 384 + d] * a + fwp[0 * 384 + 128 + d] * bsl + fwp[0 * 384 + 256 + d] * cw;
            p1 += fwp[1 * 384 + d] * a + fwp[1 * 384 + 128 + d] * bsl + fwp[1 * 384 + 256 + d] * cw;
            p2 += fwp[2 * 384 + d] * a + fwp[2 * 384 + 128 + d] * bsl + fwp[2 * 384 + 256 + d] * cw;
        }
    }
    p0 += __shfl_xor(p0, 16); p0 += __shfl_xor(p0, 32);
    p1 += __shfl_xor(p1, 16); p1 += __shfl_xor(p1, 32);
    p2 += __shfl_xor(p2, 16); p2 += __shfl_xor(p2, 32);
    float mx = fmaxf(p0, fmaxf(p1, p2));
    float e0 = expf(p0 - mx), e1 = expf(p1 - mx), e2 = expf(p2 - mx);
    float inv3 = 1.f / (e0 + e1 + e2);
    float w0 = e0 * inv3, w1 = e1 * inv3, w2 = e2 * inv3;
    #pragma unroll
    for (int dt = 0; dt < 8; ++dt) {
        float4 r;
        r.x = w0 * oc[dt].x + w1 * o_acc[dt][0] + w2 * ow[dt].x;
        r.y = w0 * oc[dt].y + w1 * o_acc[dt][1] + w2 * ow[dt].y;
        r.z = w0 * oc[dt].z + w1 * o_acc[dt][2] + w2 * ow[dt].z;
        r.w = w0 * oc[dt].w + w1 * o_acc[dt][3] + w2 * ow[dt].w;
        *reinterpret_cast<float4*>(out + th * 1024 + hh * 128 + dt * 16 + g * 4) = r;
    }
}

extern "C" void kernel_launch(void* const* d_in, const int* in_sizes, int n_in,
                              void* d_out, int out_size, void* d_ws, size_t ws_size,
                              hipStream_t stream) {
    (void)in_sizes; (void)n_in; (void)out_size; (void)ws_size;
    const float* q   = (const float*)d_in[0];
    const float* k   = (const float*)d_in[1];
    const float* v   = (const float*)d_in[2];
    const float* wk  = (const float*)d_in[3];
    const float* wvg = (const float*)d_in[4];
    const float* fw  = (const float*)d_in[5];
    float* out = (float*)d_out;
    float* ws = (float*)d_ws;
    float* ck = ws;
    float* cv = ws + NCMP * 128;
    unsigned int* selmask = (unsigned int*)(ws + 2 * NCMP * 128);
    unsigned short* kbf = (unsigned short*)(ws + 2 * NCMP * 128 + 2048);
    unsigned short* vtbf = kbf + 2048 * 128;

    k_convert<<<dim3(256), dim3(256), 0, stream>>>(k, v, kbf, vtbf);
    k_compress2<<<dim3(2 * NCMP), dim3(256), 0, stream>>>(k, v, wk, wvg, ck, cv);
    k_cmp_attn<<<dim3(2048 / TB), dim3(256), 0, stream>>>(q, ck, cv, out, selmask);
    k_main<<<dim3(1024), dim3(256), 0, stream>>>(q, kbf, vtbf, selmask, fw, out);
}

// Round 10
// 209.881 us; speedup vs baseline: 1.1497x; 1.0118x over previous
//
#include <hip/hip_runtime.h>

// NSA constants
#define NCMP 127
#define SCALE 0.08838834764831845f
#define QSCALE (0.08838834764831845f * 1.4426950408889634f)  // SCALE * log2(e)
#define TB 8    // t's per WG in k_cmp_attn

typedef __attribute__((ext_vector_type(8))) short bf16x8;
typedef __attribute__((ext_vector_type(4))) float f32x4;

__device__ __forceinline__ unsigned short f2bf(float x) {
    union { float f; unsigned u; } a; a.f = x;
    unsigned r = a.u + 0x7fffu + ((a.u >> 16) & 1u);
    return (unsigned short)(r >> 16);
}
__device__ __forceinline__ float dot4(float4 a, float4 b) {
    return a.x * b.x + a.y * b.y + a.z * b.z + a.w * b.w;
}

// ------------- Kernel A: fused k+v compress (gate-pooled blocks) -------------
__global__ __launch_bounds__(256) void k_compress2(const float* __restrict__ kk,
                                                   const float* __restrict__ vv,
                                                   const float* __restrict__ wk,
                                                   const float* __restrict__ wv,
                                                   float* __restrict__ ck,
                                                   float* __restrict__ cv) {
    __shared__ float blk[4096];   // 32 x 128 f32
    __shared__ float gate[32];
    int n = blockIdx.x >> 1;
    int which = blockIdx.x & 1;
    const float* src = which ? vv : kk;
    const float* w   = which ? wv : wk;
    float* out       = which ? cv : ck;
    int tid = threadIdx.x;

    {
        const float4* sp = reinterpret_cast<const float4*>(src + n * 16 * 128);
        float4* bp = reinterpret_cast<float4*>(blk);
        #pragma unroll
        for (int i = 0; i < 4; ++i) bp[tid + 256 * i] = sp[tid + 256 * i];
    }
    __syncthreads();

    {
        int j = tid >> 3, sub = tid & 7;
        const float4* wp = reinterpret_cast<const float4*>(w + j * 4096);
        const float4* bp = reinterpret_cast<const float4*>(blk);
        float s0 = 0.f, s1 = 0.f, s2 = 0.f, s3 = 0.f;
        for (int i = sub * 4; i < 1024; i += 32) {
            float4 w0 = wp[i], w1 = wp[i + 1], w2 = wp[i + 2], w3 = wp[i + 3];
            s0 += dot4(bp[i], w0);
            s1 += dot4(bp[i + 1], w1);
            s2 += dot4(bp[i + 2], w2);
            s3 += dot4(bp[i + 3], w3);
        }
        float s = (s0 + s1) + (s2 + s3);
        s += __shfl_xor(s, 1);
        s += __shfl_xor(s, 2);
        s += __shfl_xor(s, 4);
        if (sub == 0) gate[j] = s;
    }
    __syncthreads();

    if (tid < 32) {
        float gv = gate[tid];
        float m = gv;
        #pragma unroll
        for (int off = 16; off > 0; off >>= 1) m = fmaxf(m, __shfl_xor(m, off));
        float e = expf(gv - m);
        float ss = e;
        #pragma unroll
        for (int off = 16; off > 0; off >>= 1) ss += __shfl_xor(ss, off);
        gate[tid] = e / ss;
    }
    __syncthreads();

    if (tid < 128) {
        float acc = 0.f;
        #pragma unroll
        for (int kx = 0; kx < 32; ++kx) acc += gate[kx] * blk[kx * 128 + tid];
        out[n * 128 + tid] = acc;
    }
}

// ------------- Kernel D: f32 -> bf16 convert (K row-major, V transposed) -------------
__global__ __launch_bounds__(256) void k_convert(const float* __restrict__ k,
                                                 const float* __restrict__ v,
                                                 unsigned short* __restrict__ kbf,
                                                 unsigned short* __restrict__ vtbf) {
    int bid = blockIdx.x, tid = threadIdx.x;
    {
        int idx = bid * 1024 + tid * 4;
        float4 x = *reinterpret_cast<const float4*>(k + idx);
        unsigned short o[4] = {f2bf(x.x), f2bf(x.y), f2bf(x.z), f2bf(x.w)};
        *reinterpret_cast<ulonglong1*>(kbf + idx) = *reinterpret_cast<ulonglong1*>(o);
    }
    {
        int p = bid * 8 + (tid >> 5);
        int d4 = (tid & 31) << 2;
        float4 x = *reinterpret_cast<const float4*>(v + p * 128 + d4);
        vtbf[(d4 + 0) * 2048 + p] = f2bf(x.x);
        vtbf[(d4 + 1) * 2048 + p] = f2bf(x.y);
        vtbf[(d4 + 2) * 2048 + p] = f2bf(x.z);
        vtbf[(d4 + 3) * 2048 + p] = f2bf(x.w);
    }
}

// ---------- Kernel B: compressed attention + top-k block select ----------
__global__ __launch_bounds__(256) void k_cmp_attn(const float* __restrict__ q,
                                                  const float* __restrict__ ck,
                                                  const float* __restrict__ cv,
                                                  float* __restrict__ o_cmp,
                                                  unsigned int* __restrict__ selmask) {
    __shared__ float sc[64 * 132];
    __shared__ float pg[TB * 128];
    __shared__ float slc[TB * 32];
    __shared__ float adj[TB * 32];
    int t0 = blockIdx.x * TB;
    int tid = threadIdx.x;
    int wv = tid >> 6, ln = tid & 63;

    {
        int rh = wv >> 1, nh = wv & 1;
        int rg = ln >> 3, ds = ln & 7;
        int d0 = ds * 16;
        float4 qr[4][4];
        #pragma unroll
        for (int rr = 0; rr < 4; ++rr) {
            int r = rh * 32 + rg * 4 + rr;
            const float4* qp = reinterpret_cast<const float4*>(
                q + (t0 + (r >> 3)) * 1024 + (r & 7) * 128 + d0);
            #pragma unroll
            for (int cc = 0; cc < 4; ++cc) qr[rr][cc] = qp[cc];
        }
        for (int jn = 0; jn < 64; ++jn) {
            int n = nh * 64 + jn;
            if (n >= NCMP) break;
            const float4* kp = reinterpret_cast<const float4*>(ck + n * 128 + d0);
            float4 k0 = kp[0], k1 = kp[1], k2 = kp[2], k3 = kp[3];
            float part[4];
            #pragma unroll
            for (int rr = 0; rr < 4; ++rr)
                part[rr] = dot4(qr[rr][0], k0) + dot4(qr[rr][1], k1) +
                           dot4(qr[rr][2], k2) + dot4(qr[rr][3], k3);
            #pragma unroll
            for (int off = 1; off < 8; off <<= 1)
                #pragma unroll
                for (int rr = 0; rr < 4; ++rr) part[rr] += __shfl_xor(part[rr], off);
            if (ds == 0) {
                #pragma unroll
                for (int rr = 0; rr < 4; ++rr)
                    sc[(rh * 32 + rg * 4 + rr) * 132 + n] = part[rr] * SCALE;
            }
        }
    }
    __syncthreads();

    {
        int r = wv * 16 + (ln >> 2);
        int nl = ln & 3;
        int t = t0 + (r >> 3);
        int nvalid = (t >= 31) ? (((t - 31) >> 4) + 1) : 0;
        if (nvalid > NCMP) nvalid = NCMP;
        float* row = sc + r * 132;
        float m = -3e38f;
        for (int n = nl; n < nvalid; n += 4) m = fmaxf(m, row[n]);
        m = fmaxf(m, __shfl_xor(m, 1));
        m = fmaxf(m, __shfl_xor(m, 2));
        float ss = 0.f;
        for (int n = nl; n < 128; n += 4) {
            float e = (n < nvalid) ? expf(row[n] - m) : 0.f;
            ss += e;
            row[n] = e;
        }
        ss += __shfl_xor(ss, 1);
        ss += __shfl_xor(ss, 2);
        float inv = (ss > 0.f) ? 1.f / ss : 0.f;
        for (int n = nl; n < 128; n += 4) row[n] *= inv;
    }
    __syncthreads();

    {
        int rg = ln >> 3, ds = ln & 7, d0 = ds * 16;
        int rbase = wv * 16 + rg * 2;
        int nvmax = (t0 + 7 >= 31) ? (((t0 + 7 - 31) >> 4) + 1) : 0;
        if (nvmax > NCMP) nvmax = NCMP;
        float4 acc[2][4];
        #pragma unroll
        for (int rr = 0; rr < 2; ++rr)
            #pragma unroll
            for (int cc = 0; cc < 4; ++cc) acc[rr][cc] = (float4){0.f, 0.f, 0.f, 0.f};
        for (int n = 0; n < nvmax; ++n) {
            const float4* vp = reinterpret_cast<const float4*>(cv + n * 128 + d0);
            float4 v0 = vp[0], v1 = vp[1], v2 = vp[2], v3 = vp[3];
            #pragma unroll
            for (int rr = 0; rr < 2; ++rr) {
                float p = sc[(rbase + rr) * 132 + n];
                acc[rr][0].x += p * v0.x; acc[rr][0].y += p * v0.y; acc[rr][0].z += p * v0.z; acc[rr][0].w += p * v0.w;
                acc[rr][1].x += p * v1.x; acc[rr][1].y += p * v1.y; acc[rr][1].z += p * v1.z; acc[rr][1].w += p * v1.w;
                acc[rr][2].x += p * v2.x; acc[rr][2].y += p * v2.y; acc[rr][2].z += p * v2.z; acc[rr][2].w += p * v2.w;
                acc[rr][3].x += p * v3.x; acc[rr][3].y += p * v3.y; acc[rr][3].z += p * v3.z; acc[rr][3].w += p * v3.w;
            }
        }
        #pragma unroll
        for (int rr = 0; rr < 2; ++rr) {
            int r = rbase + rr;
            float4* op = reinterpret_cast<float4*>(
                o_cmp + (t0 + (r >> 3)) * 1024 + (r & 7) * 128 + d0);
            #pragma unroll
            for (int cc = 0; cc < 4; ++cc) op[cc] = acc[rr][cc];
        }
    }

    for (int i2 = tid; i2 < TB * 128; i2 += 256) {
        int tl = i2 >> 7, n = i2 & 127;
        float s = 0.f;
        #pragma unroll
        for (int h = 0; h < 8; ++h) s += sc[(tl * 8 + h) * 132 + n];
        pg[i2] = s;
    }
    __syncthreads();
    if (tid < TB * 32) {
        int tl = tid >> 5, s32 = tid & 31;
        float s = 0.f;
        #pragma unroll
        for (int j = 0; j < 4; ++j) {
            int n = s32 * 4 + j;
            if (n < NCMP) s += pg[tl * 128 + n];
        }
        slc[tid] = s;
    }
    __syncthreads();
    if (tid < TB) {
        int t = t0 + tid;
        int qblk = t >> 6;
        float* a = adj + tid * 32;
        for (int s = 0; s < 32; ++s) {
            if (s > qblk) a[s] = -1e30f;
            else a[s] = slc[tid * 32 + s] + ((s == 0 || s > qblk - 2) ? 1e30f : 0.f);
        }
        unsigned int msk = 0u;
        for (int it = 0; it < 16; ++it) {
            float best = -2e38f; int bi = 0;
            for (int s = 0; s < 32; ++s) { if (a[s] > best) { best = a[s]; bi = s; } }
            if (best <= -5e29f) break;
            msk |= 1u << bi;
            a[bi] = -2e38f;
        }
        selmask[t] = msk;
    }
}

// -------- Kernel C: single-branch waves, fence-pinned load batches --------
__global__ __launch_bounds__(256, 2) void k_main(const float* __restrict__ q,
                                              const unsigned short* __restrict__ kbf,
                                              const unsigned short* __restrict__ vtbf,
                                              const unsigned int* __restrict__ selmask,
                                              const float* __restrict__ fw,
                                              float* __restrict__ out) {
    __shared__ float mrg[2][16 * 132];             // per-branch merge buffers
    __shared__ float mlbuf[4][16][2];              // wave, row, {m,l}

    // Anti-symmetric balance: CU r hosts bids {r, r+256, r+512, r+768};
    // pair-sum per CU = 2046 (constant).
    int bid = blockIdx.x;
    int jr = bid >> 8, rr_ = bid & 255;
    int pairidx = (jr << 8) | ((jr & 1) ? (255 - rr_) : rr_);
    int tp = pairidx * 2;

    int tid = threadIdx.x;
    int wv = tid >> 6, ln = tid & 63;
    int c = ln & 15, g = ln >> 4;
    bool is_sel = (wv < 2);
    int w = wv & 1;              // split-K parity within branch

    unsigned int sm0 = selmask[tp], sm1 = selmask[tp + 1];
    unsigned int sm_wave = sm0 | sm1;

    // per-lane q-row: row = c -> t = tp + (c>>3), h = c&7
    int th = tp + (c >> 3);
    int hh = c & 7;
    unsigned int smc = (c >> 3) ? sm1 : sm0;

    // Q fragments (B-operand for swapped QK), pre-scaled to log2 domain
    bf16x8 qf[4];
    {
        const float* qp = q + th * 1024 + hh * 128;
        #pragma unroll
        for (int ks = 0; ks < 4; ++ks) {
            int d0 = ks * 32 + g * 8;
            float4 x = *reinterpret_cast<const float4*>(qp + d0);
            float4 y = *reinterpret_cast<const float4*>(qp + d0 + 4);
            bf16x8 f;
            f[0]=(short)f2bf(x.x*QSCALE); f[1]=(short)f2bf(x.y*QSCALE); f[2]=(short)f2bf(x.z*QSCALE); f[3]=(short)f2bf(x.w*QSCALE);
            f[4]=(short)f2bf(y.x*QSCALE); f[5]=(short)f2bf(y.y*QSCALE); f[6]=(short)f2bf(y.z*QSCALE); f[7]=(short)f2bf(y.w*QSCALE);
            qf[ks] = f;
        }
    }

    float m_run = -1e30f, l_run = 0.f;
    f32x4 o_acc[8];
    #pragma unroll
    for (int dt = 0; dt < 8; ++dt) o_acc[dt] = (f32x4){0.f, 0.f, 0.f, 0.f};

    int qblk_max = (tp + 1) >> 6;
    int srcA = ((g & 1) << 5) + c;
    int srcB = srcA + 16;
    bool hi = (g >= 2);

    auto process = [&](int b) {
        const unsigned short* kb = kbf + b * 64 * 128;
        const unsigned short* vb = vtbf + b * 64;

        // ---- issue ALL 32 loads (16 K + 16 V) before any compute ----
        bf16x8 kf[4][4];
        #pragma unroll
        for (int nt = 0; nt < 4; ++nt)
            #pragma unroll
            for (int ks = 0; ks < 4; ++ks)
                kf[nt][ks] = *reinterpret_cast<const bf16x8*>(
                    kb + (nt * 16 + c) * 128 + ks * 32 + g * 8);
        bf16x8 vf[2][8];
        #pragma unroll
        for (int ks = 0; ks < 2; ++ks)
            #pragma unroll
            for (int dt = 0; dt < 8; ++dt)
                vf[ks][dt] = *reinterpret_cast<const bf16x8*>(
                    vb + (dt * 16 + c) * 2048 + ks * 32 + g * 8);
        // Pin the batch: loads may not sink below, consumers may not hoist above.
        // Forces the allocator to keep kf+vf live -> counted vmcnt, full MLP.
        __builtin_amdgcn_sched_barrier(0);

        // QK^T swapped: S[qrow=c][pos = b*64 + nt*16 + g*4 + i]
        f32x4 sacc[4];
        #pragma unroll
        for (int nt = 0; nt < 4; ++nt) {
            f32x4 acc = (f32x4){0.f, 0.f, 0.f, 0.f};
            #pragma unroll
            for (int ks = 0; ks < 4; ++ks)
                acc = __builtin_amdgcn_mfma_f32_16x16x32_bf16(kf[nt][ks], qf[ks], acc, 0, 0, 0);
            sacc[nt] = acc;
        }

        // mask + in-lane max (one q-row per lane)
        bool selbit = (smc >> b) & 1u;
        float mloc = -1e30f;
        #pragma unroll
        for (int nt = 0; nt < 4; ++nt) {
            #pragma unroll
            for (int i = 0; i < 4; ++i) {
                int pos = b * 64 + nt * 16 + g * 4 + i;
                bool val;
                if (is_sel) val = selbit && (pos <= th);
                else        val = (pos <= th) && (pos + 512 > th);
                float s = val ? sacc[nt][i] : -1e30f;
                sacc[nt][i] = s;
                mloc = fmaxf(mloc, s);
            }
        }
        mloc = fmaxf(mloc, __shfl_xor(mloc, 16));
        mloc = fmaxf(mloc, __shfl_xor(mloc, 32));
        float mn = fmaxf(m_run, mloc);
        float al = exp2f(m_run - mn);

        float lsum = 0.f;
        #pragma unroll
        for (int nt = 0; nt < 4; ++nt) {
            #pragma unroll
            for (int i = 0; i < 4; ++i) {
                float s = sacc[nt][i];
                float p = (s > -5e29f) ? exp2f(s - mn) : 0.f;
                sacc[nt][i] = p;
                lsum += p;
            }
        }
        lsum += __shfl_xor(lsum, 16);
        lsum += __shfl_xor(lsum, 32);
        m_run = mn;
        l_run = l_run * al + lsum;

        if (__any(al != 1.f)) {
            #pragma unroll
            for (int dt = 0; dt < 8; ++dt)
                #pragma unroll
                for (int i = 0; i < 4; ++i)
                    o_acc[dt][i] *= al;
        }

        // pack P rows to bf16 pairs
        unsigned int pw[8];
        #pragma unroll
        for (int nt = 0; nt < 4; ++nt) {
            unsigned int w0, w1;
            asm("v_cvt_pk_bf16_f32 %0, %1, %2" : "=v"(w0) : "v"(sacc[nt][0]), "v"(sacc[nt][1]));
            asm("v_cvt_pk_bf16_f32 %0, %1, %2" : "=v"(w1) : "v"(sacc[nt][2]), "v"(sacc[nt][3]));
            pw[2 * nt] = w0;
            pw[2 * nt + 1] = w1;
        }

        // in-register P^T B-frag assembly + PV (V already in regs)
        #pragma unroll
        for (int ks = 0; ks < 2; ++ks) {
            unsigned int a0 = __shfl(pw[4 * ks + 0], srcA);
            unsigned int a1 = __shfl(pw[4 * ks + 1], srcA);
            unsigned int a2 = __shfl(pw[4 * ks + 0], srcB);
            unsigned int a3 = __shfl(pw[4 * ks + 1], srcB);
            unsigned int b0 = __shfl(pw[4 * ks + 2], srcA);
            unsigned int b1 = __shfl(pw[4 * ks + 3], srcA);
            unsigned int b2 = __shfl(pw[4 * ks + 2], srcB);
            unsigned int b3 = __shfl(pw[4 * ks + 3], srcB);
            unsigned int wparr[4] = {hi ? b0 : a0, hi ? b1 : a1, hi ? b2 : a2, hi ? b3 : a3};
            bf16x8 pa = *reinterpret_cast<bf16x8*>(wparr);
            #pragma unroll
            for (int dt = 0; dt < 8; ++dt)
                o_acc[dt] = __builtin_amdgcn_mfma_f32_16x16x32_bf16(vf[ks][dt], pa, o_acc[dt], 0, 0, 0);
        }
    };

    if (is_sel) {
        unsigned int mm = sm_wave;
        if (qblk_max < 31) mm &= (1u << (qblk_max + 1)) - 1u;
        int idx = 0;
        while (mm) {
            int b = __builtin_ctz(mm);
            mm &= mm - 1;
            if ((idx++ & 1) == w) process(b);
        }
    } else {
        int wlo = (tp >= 575) ? (((tp - 575) >> 6) + 1) : 0;
        for (int b = wlo + w; b <= qblk_max; b += 2) process(b);
    }

    // ---- merge: wave1 -> wave0 (select), wave3 -> wave2 (window) ----
    if (w == 1) {
        if (g == 0) { mlbuf[wv][c][0] = m_run; mlbuf[wv][c][1] = l_run; }
        #pragma unroll
        for (int dt = 0; dt < 8; ++dt)
            *reinterpret_cast<float4*>(&mrg[wv >> 1][c * 132 + dt * 16 + g * 4]) =
                (float4){o_acc[dt][0], o_acc[dt][1], o_acc[dt][2], o_acc[dt][3]};
    }
    __syncthreads();
    if (w == 0) {
        float m1 = mlbuf[wv + 1][c][0];
        float l1 = mlbuf[wv + 1][c][1];
        float mn = fmaxf(m_run, m1);
        float a0 = exp2f(m_run - mn), a1 = exp2f(m1 - mn);
        l_run = a0 * l_run + a1 * l1;
        float inv = 1.f / l_run;
        #pragma unroll
        for (int dt = 0; dt < 8; ++dt) {
            float4 o1 = *reinterpret_cast<const float4*>(&mrg[wv >> 1][c * 132 + dt * 16 + g * 4]);
            o_acc[dt][0] = (a0 * o_acc[dt][0] + a1 * o1.x) * inv;
            o_acc[dt][1] = (a0 * o_acc[dt][1] + a1 * o1.y) * inv;
            o_acc[dt][2] = (a0 * o_acc[dt][2] + a1 * o1.z) * inv;
            o_acc[dt][3] = (a0 * o_acc[dt][3] + a1 * o1.w) * inv;
        }
    }
    // wave 2 publishes final (normalized) o_sw
    if (wv == 2) {
        #pragma unroll
        for (int dt = 0; dt < 8; ++dt)
            *reinterpret_cast<float4*>(&mrg[1][c * 132 + dt * 16 + g * 4]) =
                (float4){o_acc[dt][0], o_acc[dt][1], o_acc[dt][2], o_acc[dt][3]};
    }
    __syncthreads();
    if (wv != 0) return;

    // ---- fusion epilogue (wave 0: o_sel in regs, o_sw in mrg[1], o_cmp in out) ----
    float4 oc[8], ow[8];
    #pragma unroll
    for (int dt = 0; dt < 8; ++dt) {
        oc[dt] = *reinterpret_cast<const float4*>(out + th * 1024 + hh * 128 + dt * 16 + g * 4);
        ow[dt] = *reinterpret_cast<const float4*>(&mrg[1][c * 132 + dt * 16 + g * 4]);
    }
    const float* fwp = fw + hh * 3 * 384;
    float p0 = 0.f, p1 = 0.f, p2 = 0.f;
    #pragma unroll
    for (int dt = 0; dt < 8; ++dt) {
        #pragma unroll
        for (int i = 0; i < 4; ++i) {
            int d = dt * 16 + g * 4 + i;
            float a = (i == 0) ? oc[dt].x : (i == 1) ? oc[dt].y : (i == 2) ? oc[dt].z : oc[dt].w;
            float bsl = o_acc[dt][i];
            float cw = (i == 0) ? ow[dt].x : (i == 1) ? ow[dt].y : (i == 2) ? ow[dt].z : ow[dt].w;
            p0 += fwp[0 * 384 + d] * a + fwp[0 * 384 + 128 + d] * bsl + fwp[0 * 384 + 256 + d] * cw;
            p1 += fwp[1 * 384 + d] * a + fwp[1 * 384 + 128 + d] * bsl + fwp[1 * 384 + 256 + d] * cw;
            p2 += fwp[2 * 384 + d] * a + fwp[2 * 384 + 128 + d] * bsl + fwp[2 * 384 + 256 + d] * cw;
        }
    }
    p0 += __shfl_xor(p0, 16); p0 += __shfl_xor(p0, 32);
    p1 += __shfl_xor(p1, 16); p1 += __shfl_xor(p1, 32);
    p2 += __shfl_xor(p2, 16); p2 += __shfl_xor(p2, 32);
    float mx = fmaxf(p0, fmaxf(p1, p2));
    float e0 = expf(p0 - mx), e1 = expf(p1 - mx), e2 = expf(p2 - mx);
    float inv3 = 1.f / (e0 + e1 + e2);
    float w0 = e0 * inv3, w1 = e1 * inv3, w2 = e2 * inv3;
    #pragma unroll
    for (int dt = 0; dt < 8; ++dt) {
        float4 r;
        r.x = w0 * oc[dt].x + w1 * o_acc[dt][0] + w2 * ow[dt].x;
        r.y = w0 * oc[dt].y + w1 * o_acc[dt][1] + w2 * ow[dt].y;
        r.z = w0 * oc[dt].z + w1 * o_acc[dt][2] + w2 * ow[dt].z;
        r.w = w0 * oc[dt].w + w1 * o_acc[dt][3] + w2 * ow[dt].w;
        *reinterpret_cast<float4*>(out + th * 1024 + hh * 128 + dt * 16 + g * 4) = r;
    }
}

extern "C" void kernel_launch(void* const* d_in, const int* in_sizes, int n_in,
                              void* d_out, int out_size, void* d_ws, size_t ws_size,
                              hipStream_t stream) {
    (void)in_sizes; (void)n_in; (void)out_size; (void)ws_size;
    const float* q   = (const float*)d_in[0];
    const float* k   = (const float*)d_in[1];
    const float* v   = (const float*)d_in[2];
    const float* wk  = (const float*)d_in[3];
    const float* wvg = (const float*)d_in[4];
    const float* fw  = (const float*)d_in[5];
    float* out = (float*)d_out;
    float* ws = (float*)d_ws;
    float* ck = ws;
    float* cv = ws + NCMP * 128;
    unsigned int* selmask = (unsigned int*)(ws + 2 * NCMP * 128);
    unsigned short* kbf = (unsigned short*)(ws + 2 * NCMP * 128 + 2048);
    unsigned short* vtbf = kbf + 2048 * 128;

    k_convert<<<dim3(256), dim3(256), 0, stream>>>(k, v, kbf, vtbf);
    k_compress2<<<dim3(2 * NCMP), dim3(256), 0, stream>>>(k, v, wk, wvg, ck, cv);
    k_cmp_attn<<<dim3(2048 / TB), dim3(256), 0, stream>>>(q, ck, cv, out, selmask);
    k_main<<<dim3(1024), dim3(256), 0, stream>>>(q, kbf, vtbf, selmask, fw, out);
}

// Round 11
// 200.151 us; speedup vs baseline: 1.2056x; 1.0486x over previous
//
#include <hip/hip_runtime.h>

// NSA constants
#define NCMP 127
#define SCALE 0.08838834764831845f
#define QSCALE (0.08838834764831845f * 1.4426950408889634f)  // SCALE * log2(e)
#define TB 8    // t's per WG in k_cmp_attn
#define TQ 4    // t's per WG in k_main

typedef __attribute__((ext_vector_type(8))) short bf16x8;
typedef __attribute__((ext_vector_type(4))) float f32x4;

__device__ __forceinline__ unsigned short f2bf(float x) {
    union { float f; unsigned u; } a; a.f = x;
    unsigned r = a.u + 0x7fffu + ((a.u >> 16) & 1u);
    return (unsigned short)(r >> 16);
}
__device__ __forceinline__ float dot4(float4 a, float4 b) {
    return a.x * b.x + a.y * b.y + a.z * b.z + a.w * b.w;
}
__device__ __forceinline__ void gload_lds16(const void* g, void* l) {
    __builtin_amdgcn_global_load_lds(
        (const __attribute__((address_space(1))) unsigned int*)g,
        (__attribute__((address_space(3))) unsigned int*)l, 16, 0, 0);
}

// ------------- Kernel A: fused k+v compress (gate-pooled blocks) -------------
__global__ __launch_bounds__(256) void k_compress2(const float* __restrict__ kk,
                                                   const float* __restrict__ vv,
                                                   const float* __restrict__ wk,
                                                   const float* __restrict__ wv,
                                                   float* __restrict__ ck,
                                                   float* __restrict__ cv) {
    __shared__ float blk[4096];   // 32 x 128 f32
    __shared__ float gate[32];
    int n = blockIdx.x >> 1;
    int which = blockIdx.x & 1;
    const float* src = which ? vv : kk;
    const float* w   = which ? wv : wk;
    float* out       = which ? cv : ck;
    int tid = threadIdx.x;

    {
        const float4* sp = reinterpret_cast<const float4*>(src + n * 16 * 128);
        float4* bp = reinterpret_cast<float4*>(blk);
        #pragma unroll
        for (int i = 0; i < 4; ++i) bp[tid + 256 * i] = sp[tid + 256 * i];
    }
    __syncthreads();

    {
        int j = tid >> 3, sub = tid & 7;
        const float4* wp = reinterpret_cast<const float4*>(w + j * 4096);
        const float4* bp = reinterpret_cast<const float4*>(blk);
        float s0 = 0.f, s1 = 0.f, s2 = 0.f, s3 = 0.f;
        for (int i = sub * 4; i < 1024; i += 32) {
            float4 w0 = wp[i], w1 = wp[i + 1], w2 = wp[i + 2], w3 = wp[i + 3];
            s0 += dot4(bp[i], w0);
            s1 += dot4(bp[i + 1], w1);
            s2 += dot4(bp[i + 2], w2);
            s3 += dot4(bp[i + 3], w3);
        }
        float s = (s0 + s1) + (s2 + s3);
        s += __shfl_xor(s, 1);
        s += __shfl_xor(s, 2);
        s += __shfl_xor(s, 4);
        if (sub == 0) gate[j] = s;
    }
    __syncthreads();

    if (tid < 32) {
        float gv = gate[tid];
        float m = gv;
        #pragma unroll
        for (int off = 16; off > 0; off >>= 1) m = fmaxf(m, __shfl_xor(m, off));
        float e = expf(gv - m);
        float ss = e;
        #pragma unroll
        for (int off = 16; off > 0; off >>= 1) ss += __shfl_xor(ss, off);
        gate[tid] = e / ss;
    }
    __syncthreads();

    if (tid < 128) {
        float acc = 0.f;
        #pragma unroll
        for (int kx = 0; kx < 32; ++kx) acc += gate[kx] * blk[kx * 128 + tid];
        out[n * 128 + tid] = acc;
    }
}

// ---- Kernel D: f32 -> bf16, swizzled layouts for LDS staging ----
// kswz: row-major [2048][128] bf16, byte offset within row XOR'd by ((row&7)<<4)
// vswz: blocked [32][128 d][64 p] bf16, byte offset within d-row XOR'd by ((d&7)<<4)
__global__ __launch_bounds__(256) void k_convert(const float* __restrict__ k,
                                                 const float* __restrict__ v,
                                                 unsigned short* __restrict__ kswz,
                                                 unsigned short* __restrict__ vswz) {
    int bid = blockIdx.x, tid = threadIdx.x;
    {
        int idx = bid * 1024 + tid * 4;       // element index
        int row = idx >> 7, d = idx & 127;
        float4 x = *reinterpret_cast<const float4*>(k + idx);
        unsigned short o[4] = {f2bf(x.x), f2bf(x.y), f2bf(x.z), f2bf(x.w)};
        char* dst = (char*)kswz + row * 256 + ((d * 2) ^ ((row & 7) << 4));
        *reinterpret_cast<unsigned long long*>(dst) = *reinterpret_cast<unsigned long long*>(o);
    }
    {
        int p = bid * 8 + (tid >> 5);
        int b = p >> 6, pl = p & 63;
        int d4 = (tid & 31) << 2;
        float4 x = *reinterpret_cast<const float4*>(v + p * 128 + d4);
        unsigned short e[4] = {f2bf(x.x), f2bf(x.y), f2bf(x.z), f2bf(x.w)};
        char* vb = (char*)vswz + b * 16384;
        #pragma unroll
        for (int j = 0; j < 4; ++j) {
            int d = d4 + j;
            *reinterpret_cast<unsigned short*>(vb + d * 128 + ((pl * 2) ^ ((d & 7) << 4))) = e[j];
        }
    }
}

// ---------- Kernel B: compressed attention + top-k block select ----------
__global__ __launch_bounds__(256) void k_cmp_attn(const float* __restrict__ q,
                                                  const float* __restrict__ ck,
                                                  const float* __restrict__ cv,
                                                  float* __restrict__ o_cmp,
                                                  unsigned int* __restrict__ selmask) {
    __shared__ float sc[64 * 132];
    __shared__ float pg[TB * 128];
    __shared__ float slc[TB * 32];
    __shared__ float adj[TB * 32];
    int t0 = blockIdx.x * TB;
    int tid = threadIdx.x;
    int wv = tid >> 6, ln = tid & 63;

    {
        int rh = wv >> 1, nh = wv & 1;
        int rg = ln >> 3, ds = ln & 7;
        int d0 = ds * 16;
        float4 qr[4][4];
        #pragma unroll
        for (int rr = 0; rr < 4; ++rr) {
            int r = rh * 32 + rg * 4 + rr;
            const float4* qp = reinterpret_cast<const float4*>(
                q + (t0 + (r >> 3)) * 1024 + (r & 7) * 128 + d0);
            #pragma unroll
            for (int cc = 0; cc < 4; ++cc) qr[rr][cc] = qp[cc];
        }
        for (int jn = 0; jn < 64; ++jn) {
            int n = nh * 64 + jn;
            if (n >= NCMP) break;
            const float4* kp = reinterpret_cast<const float4*>(ck + n * 128 + d0);
            float4 k0 = kp[0], k1 = kp[1], k2 = kp[2], k3 = kp[3];
            float part[4];
            #pragma unroll
            for (int rr = 0; rr < 4; ++rr)
                part[rr] = dot4(qr[rr][0], k0) + dot4(qr[rr][1], k1) +
                           dot4(qr[rr][2], k2) + dot4(qr[rr][3], k3);
            #pragma unroll
            for (int off = 1; off < 8; off <<= 1)
                #pragma unroll
                for (int rr = 0; rr < 4; ++rr) part[rr] += __shfl_xor(part[rr], off);
            if (ds == 0) {
                #pragma unroll
                for (int rr = 0; rr < 4; ++rr)
                    sc[(rh * 32 + rg * 4 + rr) * 132 + n] = part[rr] * SCALE;
            }
        }
    }
    __syncthreads();

    {
        int r = wv * 16 + (ln >> 2);
        int nl = ln & 3;
        int t = t0 + (r >> 3);
        int nvalid = (t >= 31) ? (((t - 31) >> 4) + 1) : 0;
        if (nvalid > NCMP) nvalid = NCMP;
        float* row = sc + r * 132;
        float m = -3e38f;
        for (int n = nl; n < nvalid; n += 4) m = fmaxf(m, row[n]);
        m = fmaxf(m, __shfl_xor(m, 1));
        m = fmaxf(m, __shfl_xor(m, 2));
        float ss = 0.f;
        for (int n = nl; n < 128; n += 4) {
            float e = (n < nvalid) ? expf(row[n] - m) : 0.f;
            ss += e;
            row[n] = e;
        }
        ss += __shfl_xor(ss, 1);
        ss += __shfl_xor(ss, 2);
        float inv = (ss > 0.f) ? 1.f / ss : 0.f;
        for (int n = nl; n < 128; n += 4) row[n] *= inv;
    }
    __syncthreads();

    {
        int rg = ln >> 3, ds = ln & 7, d0 = ds * 16;
        int rbase = wv * 16 + rg * 2;
        int nvmax = (t0 + 7 >= 31) ? (((t0 + 7 - 31) >> 4) + 1) : 0;
        if (nvmax > NCMP) nvmax = NCMP;
        float4 acc[2][4];
        #pragma unroll
        for (int rr = 0; rr < 2; ++rr)
            #pragma unroll
            for (int cc = 0; cc < 4; ++cc) acc[rr][cc] = (float4){0.f, 0.f, 0.f, 0.f};
        for (int n = 0; n < nvmax; ++n) {
            const float4* vp = reinterpret_cast<const float4*>(cv + n * 128 + d0);
            float4 v0 = vp[0], v1 = vp[1], v2 = vp[2], v3 = vp[3];
            #pragma unroll
            for (int rr = 0; rr < 2; ++rr) {
                float p = sc[(rbase + rr) * 132 + n];
                acc[rr][0].x += p * v0.x; acc[rr][0].y += p * v0.y; acc[rr][0].z += p * v0.z; acc[rr][0].w += p * v0.w;
                acc[rr][1].x += p * v1.x; acc[rr][1].y += p * v1.y; acc[rr][1].z += p * v1.z; acc[rr][1].w += p * v1.w;
                acc[rr][2].x += p * v2.x; acc[rr][2].y += p * v2.y; acc[rr][2].z += p * v2.z; acc[rr][2].w += p * v2.w;
                acc[rr][3].x += p * v3.x; acc[rr][3].y += p * v3.y; acc[rr][3].z += p * v3.z; acc[rr][3].w += p * v3.w;
            }
        }
        #pragma unroll
        for (int rr = 0; rr < 2; ++rr) {
            int r = rbase + rr;
            float4* op = reinterpret_cast<float4*>(
                o_cmp + (t0 + (r >> 3)) * 1024 + (r & 7) * 128 + d0);
            #pragma unroll
            for (int cc = 0; cc < 4; ++cc) op[cc] = acc[rr][cc];
        }
    }

    for (int i2 = tid; i2 < TB * 128; i2 += 256) {
        int tl = i2 >> 7, n = i2 & 127;
        float s = 0.f;
        #pragma unroll
        for (int h = 0; h < 8; ++h) s += sc[(tl * 8 + h) * 132 + n];
        pg[i2] = s;
    }
    __syncthreads();
    if (tid < TB * 32) {
        int tl = tid >> 5, s32 = tid & 31;
        float s = 0.f;
        #pragma unroll
        for (int j = 0; j < 4; ++j) {
            int n = s32 * 4 + j;
            if (n < NCMP) s += pg[tl * 128 + n];
        }
        slc[tid] = s;
    }
    __syncthreads();
    if (tid < TB) {
        int t = t0 + tid;
        int qblk = t >> 6;
        float* a = adj + tid * 32;
        for (int s = 0; s < 32; ++s) {
            if (s > qblk) a[s] = -1e30f;
            else a[s] = slc[tid * 32 + s] + ((s == 0 || s > qblk - 2) ? 1e30f : 0.f);
        }
        unsigned int msk = 0u;
        for (int it = 0; it < 16; ++it) {
            float best = -2e38f; int bi = 0;
            for (int s = 0; s < 32; ++s) { if (a[s] > best) { best = a[s]; bi = s; } }
            if (best <= -5e29f) break;
            msk |= 1u << bi;
            a[bi] = -2e38f;
        }
        selmask[t] = msk;
    }
}

// -------- Kernel C: 4 t's/WG, LDS-staged tiles, 1-block-ahead prefetch --------
// waves: 0 = sel(t0,t1), 1 = sel(t2,t3), 2 = win(t0,t1), 3 = win(t2,t3)
__global__ __launch_bounds__(256, 2) void k_main(const float* __restrict__ q,
                                              const unsigned short* __restrict__ kswz,
                                              const unsigned short* __restrict__ vswz,
                                              const unsigned int* __restrict__ selmask,
                                              const float* __restrict__ fw,
                                              float* __restrict__ out) {
    __shared__ float smemf[16384];   // 64 KB: 2 x (16KB K-tile + 16KB V-tile); aliased by owbuf after loop
    char* smem = (char*)smemf;

    // anti-symmetric balance over 2 rounds of 256: CU r gets quads {r, 511-r}
    int bid = blockIdx.x;
    int quad = (bid < 256) ? bid : (767 - bid);
    int tq = quad * TQ;

    int tid = threadIdx.x;
    int wv = tid >> 6, ln = tid & 63;
    int c = ln & 15, g = ln >> 4;
    int pairsel = wv & 1;
    bool is_sel = (wv < 2);
    int tp = tq + 2 * pairsel;

    unsigned int s0 = selmask[tq], s1 = selmask[tq + 1],
                 s2 = selmask[tq + 2], s3 = selmask[tq + 3];
    unsigned int sm_pair = pairsel ? (s2 | s3) : (s0 | s1);

    int th = tp + (c >> 3);
    int hh = c & 7;
    int ti = 2 * pairsel + (c >> 3);
    unsigned int smc = (ti == 0) ? s0 : (ti == 1) ? s1 : (ti == 2) ? s2 : s3;

    // Q fragments (B-operand for swapped QK), pre-scaled to log2 domain
    bf16x8 qf[4];
    {
        const float* qp = q + th * 1024 + hh * 128;
        #pragma unroll
        for (int ks = 0; ks < 4; ++ks) {
            int d0 = ks * 32 + g * 8;
            float4 x = *reinterpret_cast<const float4*>(qp + d0);
            float4 y = *reinterpret_cast<const float4*>(qp + d0 + 4);
            bf16x8 f;
            f[0]=(short)f2bf(x.x*QSCALE); f[1]=(short)f2bf(x.y*QSCALE); f[2]=(short)f2bf(x.z*QSCALE); f[3]=(short)f2bf(x.w*QSCALE);
            f[4]=(short)f2bf(y.x*QSCALE); f[5]=(short)f2bf(y.y*QSCALE); f[6]=(short)f2bf(y.z*QSCALE); f[7]=(short)f2bf(y.w*QSCALE);
            qf[ks] = f;
        }
    }

    // union block list over 4 t's (sel | window), uniform across WG
    int qmax_all = (tq + 3) >> 6;
    int qmax_pair = (tp + 1) >> 6;
    unsigned int all4 = (qmax_all >= 31) ? 0xFFFFFFFFu : ((1u << (qmax_all + 1)) - 1u);
    int wlo_min = (tq >= 575) ? (((tq - 575) >> 6) + 1) : 0;
    unsigned int win4 = all4 & ~((1u << wlo_min) - 1u);
    unsigned int mm_u = ((s0 | s1 | s2 | s3) & all4) | win4;

    float m_run = -1e30f, l_run = 0.f;
    f32x4 o_acc[8];
    #pragma unroll
    for (int dt = 0; dt < 8; ++dt) o_acc[dt] = (f32x4){0.f, 0.f, 0.f, 0.f};

    int srcA = ((g & 1) << 5) + c;
    int srcB = srcA + 16;
    bool hi = (g >= 2);

    // stage one block's K+V tile (32KB) into LDS at byte offset `buf`
    auto stage = [&](int buf, int b) {
        const char* ks = (const char*)kswz + b * 16384;
        const char* vs = (const char*)vswz + b * 16384;
        char* kd = smem + buf;
        char* vd = kd + 16384;
        int lo = wv * 1024;
        int so = lo + ln * 16;
        #pragma unroll
        for (int j = 0; j < 4; ++j) {
            gload_lds16(ks + j * 4096 + so, kd + j * 4096 + lo);
            gload_lds16(vs + j * 4096 + so, vd + j * 4096 + lo);
        }
    };

    auto compute = [&](int buf, int b) {
        bool active = is_sel ? ((((sm_pair >> b) & 1u) != 0u) && b <= qmax_pair)
                             : ((b * 64 + 575 > tp) && b <= qmax_pair);
        if (!active) return;
        const char* kl = smem + buf;
        const char* vl = kl + 16384;
        int z = (c & 7) << 4;

        // QK^T swapped: S[qrow=c][pos = b*64 + nt*16 + g*4 + i]
        f32x4 sacc[4];
        #pragma unroll
        for (int nt = 0; nt < 4; ++nt) {
            f32x4 acc = (f32x4){0.f, 0.f, 0.f, 0.f};
            #pragma unroll
            for (int ks = 0; ks < 4; ++ks) {
                bf16x8 kf = *reinterpret_cast<const bf16x8*>(
                    kl + (nt * 16 + c) * 256 + ((ks * 64 + g * 16) ^ z));
                acc = __builtin_amdgcn_mfma_f32_16x16x32_bf16(kf, qf[ks], acc, 0, 0, 0);
            }
            sacc[nt] = acc;
        }

        bool selbit = (smc >> b) & 1u;
        float mloc = -1e30f;
        #pragma unroll
        for (int nt = 0; nt < 4; ++nt) {
            #pragma unroll
            for (int i = 0; i < 4; ++i) {
                int pos = b * 64 + nt * 16 + g * 4 + i;
                bool val;
                if (is_sel) val = selbit && (pos <= th);
                else        val = (pos <= th) && (pos + 512 > th);
                float s = val ? sacc[nt][i] : -1e30f;
                sacc[nt][i] = s;
                mloc = fmaxf(mloc, s);
            }
        }
        mloc = fmaxf(mloc, __shfl_xor(mloc, 16));
        mloc = fmaxf(mloc, __shfl_xor(mloc, 32));
        float mn = fmaxf(m_run, mloc);
        float al = exp2f(m_run - mn);

        float lsum = 0.f;
        #pragma unroll
        for (int nt = 0; nt < 4; ++nt) {
            #pragma unroll
            for (int i = 0; i < 4; ++i) {
                float s = sacc[nt][i];
                float p = (s > -5e29f) ? exp2f(s - mn) : 0.f;
                sacc[nt][i] = p;
                lsum += p;
            }
        }
        lsum += __shfl_xor(lsum, 16);
        lsum += __shfl_xor(lsum, 32);
        m_run = mn;
        l_run = l_run * al + lsum;

        if (__any(al != 1.f)) {
            #pragma unroll
            for (int dt = 0; dt < 8; ++dt)
                #pragma unroll
                for (int i = 0; i < 4; ++i)
                    o_acc[dt][i] *= al;
        }

        unsigned int pw[8];
        #pragma unroll
        for (int nt = 0; nt < 4; ++nt) {
            unsigned int w0, w1;
            asm("v_cvt_pk_bf16_f32 %0, %1, %2" : "=v"(w0) : "v"(sacc[nt][0]), "v"(sacc[nt][1]));
            asm("v_cvt_pk_bf16_f32 %0, %1, %2" : "=v"(w1) : "v"(sacc[nt][2]), "v"(sacc[nt][3]));
            pw[2 * nt] = w0;
            pw[2 * nt + 1] = w1;
        }

        #pragma unroll
        for (int ks = 0; ks < 2; ++ks) {
            unsigned int a0 = __shfl(pw[4 * ks + 0], srcA);
            unsigned int a1 = __shfl(pw[4 * ks + 1], srcA);
            unsigned int a2 = __shfl(pw[4 * ks + 0], srcB);
            unsigned int a3 = __shfl(pw[4 * ks + 1], srcB);
            unsigned int b0 = __shfl(pw[4 * ks + 2], srcA);
            unsigned int b1 = __shfl(pw[4 * ks + 3], srcA);
            unsigned int b2 = __shfl(pw[4 * ks + 2], srcB);
            unsigned int b3 = __shfl(pw[4 * ks + 3], srcB);
            unsigned int wparr[4] = {hi ? b0 : a0, hi ? b1 : a1, hi ? b2 : a2, hi ? b3 : a3};
            bf16x8 pa = *reinterpret_cast<bf16x8*>(wparr);
            #pragma unroll
            for (int dt = 0; dt < 8; ++dt) {
                bf16x8 vfr = *reinterpret_cast<const bf16x8*>(
                    vl + (dt * 16 + c) * 128 + ((ks * 64 + g * 16) ^ z));
                o_acc[dt] = __builtin_amdgcn_mfma_f32_16x16x32_bf16(vfr, pa, o_acc[dt], 0, 0, 0);
            }
        }
    };

    // ---- pipelined block loop: stage(next) overlaps compute(cur) ----
    unsigned int mm_c = mm_u, mm_s = mm_u;
    {
        int b0 = __builtin_ctz(mm_s); mm_s &= mm_s - 1;
        stage(0, b0);
    }
    __syncthreads();
    for (;;) {
        int b = __builtin_ctz(mm_c); mm_c &= mm_c - 1;
        if (mm_s) { int bn = __builtin_ctz(mm_s); mm_s &= mm_s - 1; stage(32768, bn); }
        compute(0, b);
        __syncthreads();
        if (!mm_c) break;
        b = __builtin_ctz(mm_c); mm_c &= mm_c - 1;
        if (mm_s) { int bn = __builtin_ctz(mm_s); mm_s &= mm_s - 1; stage(0, bn); }
        compute(32768, b);
        __syncthreads();
        if (!mm_c) break;
    }

    // ---- normalize (each wave has complete branch state; no m/l merge) ----
    {
        float invl = 1.f / l_run;
        #pragma unroll
        for (int dt = 0; dt < 8; ++dt)
            #pragma unroll
            for (int i = 0; i < 4; ++i) o_acc[dt][i] *= invl;
    }

    // win waves publish o_w (normalized) into smem (tiles dead after last barrier)
    float* owbuf = smemf;   // [2][16*132]
    if (!is_sel) {
        float* dst = owbuf + pairsel * (16 * 132) + c * 132;
        #pragma unroll
        for (int dt = 0; dt < 8; ++dt)
            *reinterpret_cast<float4*>(dst + dt * 16 + g * 4) =
                (float4){o_acc[dt][0], o_acc[dt][1], o_acc[dt][2], o_acc[dt][3]};
    }
    __syncthreads();
    if (!is_sel) return;

    // ---- fusion epilogue (sel waves: o_sel in regs, o_sw in owbuf, o_cmp in out) ----
    const float* owp = owbuf + pairsel * (16 * 132) + c * 132;
    float4 oc[8], ow[8];
    #pragma unroll
    for (int dt = 0; dt < 8; ++dt) {
        oc[dt] = *reinterpret_cast<const float4*>(out + th * 1024 + hh * 128 + dt * 16 + g * 4);
        ow[dt] = *reinterpret_cast<const float4*>(owp + dt * 16 + g * 4);
    }
    const float* fwp = fw + hh * 3 * 384;
    float p0 = 0.f, p1 = 0.f, p2 = 0.f;
    #pragma unroll
    for (int dt = 0; dt < 8; ++dt) {
        #pragma unroll
        for (int i = 0; i < 4; ++i) {
            int d = dt * 16 + g * 4 + i;
            float a = (i == 0) ? oc[dt].x : (i == 1) ? oc[dt].y : (i == 2) ? oc[dt].z : oc[dt].w;
            float bsl = o_acc[dt][i];
            float cw = (i == 0) ? ow[dt].x : (i == 1) ? ow[dt].y : (i == 2) ? ow[dt].z : ow[dt].w;
            p0 += fwp[0 * 384 + d] * a + fwp[0 * 384 + 128 + d] * bsl + fwp[0 * 384 + 256 + d] * cw;
            p1 += fwp[1 * 384 + d] * a + fwp[1 * 384 + 128 + d] * bsl + fwp[1 * 384 + 256 + d] * cw;
            p2 += fwp[2 * 384 + d] * a + fwp[2 * 384 + 128 + d] * bsl + fwp[2 * 384 + 256 + d] * cw;
        }
    }
    p0 += __shfl_xor(p0, 16); p0 += __shfl_xor(p0, 32);
    p1 += __shfl_xor(p1, 16); p1 += __shfl_xor(p1, 32);
    p2 += __shfl_xor(p2, 16); p2 += __shfl_xor(p2, 32);
    float mx = fmaxf(p0, fmaxf(p1, p2));
    float e0 = expf(p0 - mx), e1 = expf(p1 - mx), e2 = expf(p2 - mx);
    float inv3 = 1.f / (e0 + e1 + e2);
    float w0 = e0 * inv3, w1 = e1 * inv3, w2 = e2 * inv3;
    #pragma unroll
    for (int dt = 0; dt < 8; ++dt) {
        float4 r;
        r.x = w0 * oc[dt].x + w1 * o_acc[dt][0] + w2 * ow[dt].x;
        r.y = w0 * oc[dt].y + w1 * o_acc[dt][1] + w2 * ow[dt].y;
        r.z = w0 * oc[dt].z + w1 * o_acc[dt][2] + w2 * ow[dt].z;
        r.w = w0 * oc[dt].w + w1 * o_acc[dt][3] + w2 * ow[dt].w;
        *reinterpret_cast<float4*>(out + th * 1024 + hh * 128 + dt * 16 + g * 4) = r;
    }
}

extern "C" void kernel_launch(void* const* d_in, const int* in_sizes, int n_in,
                              void* d_out, int out_size, void* d_ws, size_t ws_size,
                              hipStream_t stream) {
    (void)in_sizes; (void)n_in; (void)out_size; (void)ws_size;
    const float* q   = (const float*)d_in[0];
    const float* k   = (const float*)d_in[1];
    const float* v   = (const float*)d_in[2];
    const float* wk  = (const float*)d_in[3];
    const float* wvg = (const float*)d_in[4];
    const float* fw  = (const float*)d_in[5];
    float* out = (float*)d_out;
    float* ws = (float*)d_ws;
    float* ck = ws;
    float* cv = ws + NCMP * 128;
    unsigned int* selmask = (unsigned int*)(ws + 2 * NCMP * 128);
    unsigned short* kswz = (unsigned short*)(ws + 2 * NCMP * 128 + 2048);
    unsigned short* vswz = kswz + 2048 * 128;

    k_convert<<<dim3(256), dim3(256), 0, stream>>>(k, v, kswz, vswz);
    k_compress2<<<dim3(2 * NCMP), dim3(256), 0, stream>>>(k, v, wk, wvg, ck, cv);
    k_cmp_attn<<<dim3(2048 / TB), dim3(256), 0, stream>>>(q, ck, cv, out, selmask);
    k_main<<<dim3(512), dim3(256), 0, stream>>>(q, kswz, vswz, selmask, fw, out);
}

// Round 12
// 193.313 us; speedup vs baseline: 1.2482x; 1.0354x over previous
//
#include <hip/hip_runtime.h>

// NSA constants
#define NCMP 127
#define SCALE 0.08838834764831845f
#define QSCALE (0.08838834764831845f * 1.4426950408889634f)  // SCALE * log2(e)
#define TB 8    // t's per WG in k_cmp_attn

typedef __attribute__((ext_vector_type(8))) short bf16x8;
typedef __attribute__((ext_vector_type(4))) float f32x4;

__device__ __forceinline__ unsigned short f2bf(float x) {
    union { float f; unsigned u; } a; a.f = x;
    unsigned r = a.u + 0x7fffu + ((a.u >> 16) & 1u);
    return (unsigned short)(r >> 16);
}
__device__ __forceinline__ float dot4(float4 a, float4 b) {
    return a.x * b.x + a.y * b.y + a.z * b.z + a.w * b.w;
}
__device__ __forceinline__ void gload_lds16(const void* g, void* l) {
    __builtin_amdgcn_global_load_lds(
        (const __attribute__((address_space(1))) unsigned int*)g,
        (__attribute__((address_space(3))) unsigned int*)l, 16, 0, 0);
}

// ------------- Kernel A: fused k+v compress (gate-pooled blocks) -------------
__global__ __launch_bounds__(256) void k_compress2(const float* __restrict__ kk,
                                                   const float* __restrict__ vv,
                                                   const float* __restrict__ wk,
                                                   const float* __restrict__ wv,
                                                   float* __restrict__ ck,
                                                   float* __restrict__ cv) {
    __shared__ float blk[4096];   // 32 x 128 f32
    __shared__ float gate[32];
    int n = blockIdx.x >> 1;
    int which = blockIdx.x & 1;
    const float* src = which ? vv : kk;
    const float* w   = which ? wv : wk;
    float* out       = which ? cv : ck;
    int tid = threadIdx.x;

    {
        const float4* sp = reinterpret_cast<const float4*>(src + n * 16 * 128);
        float4* bp = reinterpret_cast<float4*>(blk);
        #pragma unroll
        for (int i = 0; i < 4; ++i) bp[tid + 256 * i] = sp[tid + 256 * i];
    }
    __syncthreads();

    {
        int j = tid >> 3, sub = tid & 7;
        const float4* wp = reinterpret_cast<const float4*>(w + j * 4096);
        const float4* bp = reinterpret_cast<const float4*>(blk);
        float s0 = 0.f, s1 = 0.f, s2 = 0.f, s3 = 0.f;
        for (int i = sub * 4; i < 1024; i += 32) {
            float4 w0 = wp[i], w1 = wp[i + 1], w2 = wp[i + 2], w3 = wp[i + 3];
            s0 += dot4(bp[i], w0);
            s1 += dot4(bp[i + 1], w1);
            s2 += dot4(bp[i + 2], w2);
            s3 += dot4(bp[i + 3], w3);
        }
        float s = (s0 + s1) + (s2 + s3);
        s += __shfl_xor(s, 1);
        s += __shfl_xor(s, 2);
        s += __shfl_xor(s, 4);
        if (sub == 0) gate[j] = s;
    }
    __syncthreads();

    if (tid < 32) {
        float gv = gate[tid];
        float m = gv;
        #pragma unroll
        for (int off = 16; off > 0; off >>= 1) m = fmaxf(m, __shfl_xor(m, off));
        float e = expf(gv - m);
        float ss = e;
        #pragma unroll
        for (int off = 16; off > 0; off >>= 1) ss += __shfl_xor(ss, off);
        gate[tid] = e / ss;
    }
    __syncthreads();

    if (tid < 128) {
        float acc = 0.f;
        #pragma unroll
        for (int kx = 0; kx < 32; ++kx) acc += gate[kx] * blk[kx * 128 + tid];
        out[n * 128 + tid] = acc;
    }
}

// ---- Kernel D: f32 -> bf16, swizzled layouts for LDS staging ----
// kswz: row-major [2048][128] bf16, byte offset within row XOR'd by ((row&7)<<4)
// vswz: blocked [32][128 d][64 p] bf16, byte offset within d-row XOR'd by ((d&7)<<4)
__global__ __launch_bounds__(256) void k_convert(const float* __restrict__ k,
                                                 const float* __restrict__ v,
                                                 unsigned short* __restrict__ kswz,
                                                 unsigned short* __restrict__ vswz) {
    int bid = blockIdx.x, tid = threadIdx.x;
    {
        int idx = bid * 1024 + tid * 4;       // element index
        int row = idx >> 7, d = idx & 127;
        float4 x = *reinterpret_cast<const float4*>(k + idx);
        unsigned short o[4] = {f2bf(x.x), f2bf(x.y), f2bf(x.z), f2bf(x.w)};
        char* dst = (char*)kswz + row * 256 + ((d * 2) ^ ((row & 7) << 4));
        *reinterpret_cast<unsigned long long*>(dst) = *reinterpret_cast<unsigned long long*>(o);
    }
    {
        int p = bid * 8 + (tid >> 5);
        int b = p >> 6, pl = p & 63;
        int d4 = (tid & 31) << 2;
        float4 x = *reinterpret_cast<const float4*>(v + p * 128 + d4);
        unsigned short e[4] = {f2bf(x.x), f2bf(x.y), f2bf(x.z), f2bf(x.w)};
        char* vb = (char*)vswz + b * 16384;
        #pragma unroll
        for (int j = 0; j < 4; ++j) {
            int d = d4 + j;
            *reinterpret_cast<unsigned short*>(vb + d * 128 + ((pl * 2) ^ ((d & 7) << 4))) = e[j];
        }
    }
}

// ---------- Kernel B: compressed attention + top-k block select ----------
__global__ __launch_bounds__(256) void k_cmp_attn(const float* __restrict__ q,
                                                  const float* __restrict__ ck,
                                                  const float* __restrict__ cv,
                                                  float* __restrict__ o_cmp,
                                                  unsigned int* __restrict__ selmask) {
    __shared__ float sc[64 * 132];
    __shared__ float pg[TB * 128];
    __shared__ float slc[TB * 32];
    __shared__ float adj[TB * 32];
    int t0 = blockIdx.x * TB;
    int tid = threadIdx.x;
    int wv = tid >> 6, ln = tid & 63;

    {
        int rh = wv >> 1, nh = wv & 1;
        int rg = ln >> 3, ds = ln & 7;
        int d0 = ds * 16;
        float4 qr[4][4];
        #pragma unroll
        for (int rr = 0; rr < 4; ++rr) {
            int r = rh * 32 + rg * 4 + rr;
            const float4* qp = reinterpret_cast<const float4*>(
                q + (t0 + (r >> 3)) * 1024 + (r & 7) * 128 + d0);
            #pragma unroll
            for (int cc = 0; cc < 4; ++cc) qr[rr][cc] = qp[cc];
        }
        for (int jn = 0; jn < 64; ++jn) {
            int n = nh * 64 + jn;
            if (n >= NCMP) break;
            const float4* kp = reinterpret_cast<const float4*>(ck + n * 128 + d0);
            float4 k0 = kp[0], k1 = kp[1], k2 = kp[2], k3 = kp[3];
            float part[4];
            #pragma unroll
            for (int rr = 0; rr < 4; ++rr)
                part[rr] = dot4(qr[rr][0], k0) + dot4(qr[rr][1], k1) +
                           dot4(qr[rr][2], k2) + dot4(qr[rr][3], k3);
            #pragma unroll
            for (int off = 1; off < 8; off <<= 1)
                #pragma unroll
                for (int rr = 0; rr < 4; ++rr) part[rr] += __shfl_xor(part[rr], off);
            if (ds == 0) {
                #pragma unroll
                for (int rr = 0; rr < 4; ++rr)
                    sc[(rh * 32 + rg * 4 + rr) * 132 + n] = part[rr] * SCALE;
            }
        }
    }
    __syncthreads();

    {
        int r = wv * 16 + (ln >> 2);
        int nl = ln & 3;
        int t = t0 + (r >> 3);
        int nvalid = (t >= 31) ? (((t - 31) >> 4) + 1) : 0;
        if (nvalid > NCMP) nvalid = NCMP;
        float* row = sc + r * 132;
        float m = -3e38f;
        for (int n = nl; n < nvalid; n += 4) m = fmaxf(m, row[n]);
        m = fmaxf(m, __shfl_xor(m, 1));
        m = fmaxf(m, __shfl_xor(m, 2));
        float ss = 0.f;
        for (int n = nl; n < 128; n += 4) {
            float e = (n < nvalid) ? expf(row[n] - m) : 0.f;
            ss += e;
            row[n] = e;
        }
        ss += __shfl_xor(ss, 1);
        ss += __shfl_xor(ss, 2);
        float inv = (ss > 0.f) ? 1.f / ss : 0.f;
        for (int n = nl; n < 128; n += 4) row[n] *= inv;
    }
    __syncthreads();

    {
        int rg = ln >> 3, ds = ln & 7, d0 = ds * 16;
        int rbase = wv * 16 + rg * 2;
        int nvmax = (t0 + 7 >= 31) ? (((t0 + 7 - 31) >> 4) + 1) : 0;
        if (nvmax > NCMP) nvmax = NCMP;
        float4 acc[2][4];
        #pragma unroll
        for (int rr = 0; rr < 2; ++rr)
            #pragma unroll
            for (int cc = 0; cc < 4; ++cc) acc[rr][cc] = (float4){0.f, 0.f, 0.f, 0.f};
        for (int n = 0; n < nvmax; ++n) {
            const float4* vp = reinterpret_cast<const float4*>(cv + n * 128 + d0);
            float4 v0 = vp[0], v1 = vp[1], v2 = vp[2], v3 = vp[3];
            #pragma unroll
            for (int rr = 0; rr < 2; ++rr) {
                float p = sc[(rbase + rr) * 132 + n];
                acc[rr][0].x += p * v0.x; acc[rr][0].y += p * v0.y; acc[rr][0].z += p * v0.z; acc[rr][0].w += p * v0.w;
                acc[rr][1].x += p * v1.x; acc[rr][1].y += p * v1.y; acc[rr][1].z += p * v1.z; acc[rr][1].w += p * v1.w;
                acc[rr][2].x += p * v2.x; acc[rr][2].y += p * v2.y; acc[rr][2].z += p * v2.z; acc[rr][2].w += p * v2.w;
                acc[rr][3].x += p * v3.x; acc[rr][3].y += p * v3.y; acc[rr][3].z += p * v3.z; acc[rr][3].w += p * v3.w;
            }
        }
        #pragma unroll
        for (int rr = 0; rr < 2; ++rr) {
            int r = rbase + rr;
            float4* op = reinterpret_cast<float4*>(
                o_cmp + (t0 + (r >> 3)) * 1024 + (r & 7) * 128 + d0);
            #pragma unroll
            for (int cc = 0; cc < 4; ++cc) op[cc] = acc[rr][cc];
        }
    }

    for (int i2 = tid; i2 < TB * 128; i2 += 256) {
        int tl = i2 >> 7, n = i2 & 127;
        float s = 0.f;
        #pragma unroll
        for (int h = 0; h < 8; ++h) s += sc[(tl * 8 + h) * 132 + n];
        pg[i2] = s;
    }
    __syncthreads();
    if (tid < TB * 32) {
        int tl = tid >> 5, s32 = tid & 31;
        float s = 0.f;
        #pragma unroll
        for (int j = 0; j < 4; ++j) {
            int n = s32 * 4 + j;
            if (n < NCMP) s += pg[tl * 128 + n];
        }
        slc[tid] = s;
    }
    __syncthreads();
    if (tid < TB) {
        int t = t0 + tid;
        int qblk = t >> 6;
        float* a = adj + tid * 32;
        for (int s = 0; s < 32; ++s) {
            if (s > qblk) a[s] = -1e30f;
            else a[s] = slc[tid * 32 + s] + ((s == 0 || s > qblk - 2) ? 1e30f : 0.f);
        }
        unsigned int msk = 0u;
        for (int it = 0; it < 16; ++it) {
            float best = -2e38f; int bi = 0;
            for (int s = 0; s < 32; ++s) { if (a[s] > best) { best = a[s]; bi = s; } }
            if (best <= -5e29f) break;
            msk |= 1u << bi;
            a[bi] = -2e38f;
        }
        selmask[t] = msk;
    }
}

// -------- Kernel C: 1 t-pair/WG, single 32KB LDS tile, 4 WG/CU --------
// waves: 0,1 = select split-K (even/odd sel blocks); 2,3 = window split-K
__global__ __launch_bounds__(256, 4) void k_main(const float* __restrict__ q,
                                              const unsigned short* __restrict__ kswz,
                                              const unsigned short* __restrict__ vswz,
                                              const unsigned int* __restrict__ selmask,
                                              const float* __restrict__ fw,
                                              float* __restrict__ out) {
    __shared__ float smemf[8192];      // 32KB: K tile 16KB + V tile 16KB; aliased by mrg after loop
    __shared__ float mlbuf[4][16][2];  // wave, row, {m,l}
    char* smem = (char*)smemf;

    // heavy-first + per-CU heavy/light mix: bid<512 -> pair 1023-bid, else bid-512
    int bid = blockIdx.x;
    int pairidx = (bid < 512) ? (1023 - bid) : (bid - 512);
    int tp = pairidx * 2;

    int tid = threadIdx.x;
    int wv = tid >> 6, ln = tid & 63;
    int c = ln & 15, g = ln >> 4;
    bool is_sel = (wv < 2);
    int w = wv & 1;

    unsigned int sm0 = selmask[tp], sm1 = selmask[tp + 1];
    unsigned int sm_wave = sm0 | sm1;

    int th = tp + (c >> 3);
    int hh = c & 7;
    unsigned int smc = (c >> 3) ? sm1 : sm0;

    // Q fragments (B-operand for swapped QK), pre-scaled to log2 domain
    bf16x8 qf[4];
    {
        const float* qp = q + th * 1024 + hh * 128;
        #pragma unroll
        for (int ks = 0; ks < 4; ++ks) {
            int d0 = ks * 32 + g * 8;
            float4 x = *reinterpret_cast<const float4*>(qp + d0);
            float4 y = *reinterpret_cast<const float4*>(qp + d0 + 4);
            bf16x8 f;
            f[0]=(short)f2bf(x.x*QSCALE); f[1]=(short)f2bf(x.y*QSCALE); f[2]=(short)f2bf(x.z*QSCALE); f[3]=(short)f2bf(x.w*QSCALE);
            f[4]=(short)f2bf(y.x*QSCALE); f[5]=(short)f2bf(y.y*QSCALE); f[6]=(short)f2bf(y.z*QSCALE); f[7]=(short)f2bf(y.w*QSCALE);
            qf[ks] = f;
        }
    }

    float m_run = -1e30f, l_run = 0.f;
    f32x4 o_acc[8];
    #pragma unroll
    for (int dt = 0; dt < 8; ++dt) o_acc[dt] = (f32x4){0.f, 0.f, 0.f, 0.f};

    int qblk_max = (tp + 1) >> 6;
    int wlo = (tp >= 575) ? (((tp - 575) >> 6) + 1) : 0;
    unsigned int all = (qblk_max >= 31) ? 0xFFFFFFFFu : ((1u << (qblk_max + 1)) - 1u);
    unsigned int wmask = all & ~((1u << wlo) - 1u);
    unsigned int mm = (sm_wave & all) | wmask;     // union block list (pair)

    int srcA = ((g & 1) << 5) + c;
    int srcB = srcA + 16;
    bool hi = (g >= 2);

    // stage one block's K+V tile (32KB) into LDS
    auto stage = [&](int b) {
        const char* ks = (const char*)kswz + b * 16384;
        const char* vs = (const char*)vswz + b * 16384;
        char* kd = smem;
        char* vd = smem + 16384;
        int lo = wv * 1024;
        int so = lo + ln * 16;
        #pragma unroll
        for (int j = 0; j < 4; ++j) {
            gload_lds16(ks + j * 4096 + so, kd + j * 4096 + lo);
            gload_lds16(vs + j * 4096 + so, vd + j * 4096 + lo);
        }
    };

    auto compute = [&](int b) {
        const char* kl = smem;
        const char* vl = smem + 16384;
        int z = (c & 7) << 4;

        // QK^T swapped: S[qrow=c][pos = b*64 + nt*16 + g*4 + i]
        f32x4 sacc[4];
        #pragma unroll
        for (int nt = 0; nt < 4; ++nt) {
            f32x4 acc = (f32x4){0.f, 0.f, 0.f, 0.f};
            #pragma unroll
            for (int ks = 0; ks < 4; ++ks) {
                bf16x8 kf = *reinterpret_cast<const bf16x8*>(
                    kl + (nt * 16 + c) * 256 + ((ks * 64 + g * 16) ^ z));
                acc = __builtin_amdgcn_mfma_f32_16x16x32_bf16(kf, qf[ks], acc, 0, 0, 0);
            }
            sacc[nt] = acc;
        }

        bool selbit = (smc >> b) & 1u;
        float mloc = -1e30f;
        #pragma unroll
        for (int nt = 0; nt < 4; ++nt) {
            #pragma unroll
            for (int i = 0; i < 4; ++i) {
                int pos = b * 64 + nt * 16 + g * 4 + i;
                bool val;
                if (is_sel) val = selbit && (pos <= th);
                else        val = (pos <= th) && (pos + 512 > th);
                float s = val ? sacc[nt][i] : -1e30f;
                sacc[nt][i] = s;
                mloc = fmaxf(mloc, s);
            }
        }
        mloc = fmaxf(mloc, __shfl_xor(mloc, 16));
        mloc = fmaxf(mloc, __shfl_xor(mloc, 32));
        float mn = fmaxf(m_run, mloc);
        float al = exp2f(m_run - mn);

        float lsum = 0.f;
        #pragma unroll
        for (int nt = 0; nt < 4; ++nt) {
            #pragma unroll
            for (int i = 0; i < 4; ++i) {
                float s = sacc[nt][i];
                float p = (s > -5e29f) ? exp2f(s - mn) : 0.f;
                sacc[nt][i] = p;
                lsum += p;
            }
        }
        lsum += __shfl_xor(lsum, 16);
        lsum += __shfl_xor(lsum, 32);
        m_run = mn;
        l_run = l_run * al + lsum;

        if (__any(al != 1.f)) {
            #pragma unroll
            for (int dt = 0; dt < 8; ++dt)
                #pragma unroll
                for (int i = 0; i < 4; ++i)
                    o_acc[dt][i] *= al;
        }

        unsigned int pw[8];
        #pragma unroll
        for (int nt = 0; nt < 4; ++nt) {
            unsigned int w0, w1;
            asm("v_cvt_pk_bf16_f32 %0, %1, %2" : "=v"(w0) : "v"(sacc[nt][0]), "v"(sacc[nt][1]));
            asm("v_cvt_pk_bf16_f32 %0, %1, %2" : "=v"(w1) : "v"(sacc[nt][2]), "v"(sacc[nt][3]));
            pw[2 * nt] = w0;
            pw[2 * nt + 1] = w1;
        }

        #pragma unroll
        for (int ks = 0; ks < 2; ++ks) {
            unsigned int a0 = __shfl(pw[4 * ks + 0], srcA);
            unsigned int a1 = __shfl(pw[4 * ks + 1], srcA);
            unsigned int a2 = __shfl(pw[4 * ks + 0], srcB);
            unsigned int a3 = __shfl(pw[4 * ks + 1], srcB);
            unsigned int b0 = __shfl(pw[4 * ks + 2], srcA);
            unsigned int b1 = __shfl(pw[4 * ks + 3], srcA);
            unsigned int b2 = __shfl(pw[4 * ks + 2], srcB);
            unsigned int b3 = __shfl(pw[4 * ks + 3], srcB);
            unsigned int wparr[4] = {hi ? b0 : a0, hi ? b1 : a1, hi ? b2 : a2, hi ? b3 : a3};
            bf16x8 pa = *reinterpret_cast<bf16x8*>(wparr);
            #pragma unroll
            for (int dt = 0; dt < 8; ++dt) {
                bf16x8 vfr = *reinterpret_cast<const bf16x8*>(
                    vl + (dt * 16 + c) * 128 + ((ks * 64 + g * 16) ^ z));
                o_acc[dt] = __builtin_amdgcn_mfma_f32_16x16x32_bf16(vfr, pa, o_acc[dt], 0, 0, 0);
            }
        }
    };

    // ---- block loop: stage -> barrier -> compute(per-wave role) -> barrier ----
    int selidx = 0, winidx = 0;
    while (mm) {
        int b = __builtin_ctz(mm);
        mm &= mm - 1;
        stage(b);
        __syncthreads();
        bool act;
        if (is_sel) {
            bool sb = (sm_wave >> b) & 1u;
            act = sb && ((selidx & 1) == w);
            selidx += sb ? 1 : 0;
        } else {
            bool wb = (b * 64 + 575 > tp);
            act = wb && ((winidx & 1) == w);
            winidx += wb ? 1 : 0;
        }
        if (act) compute(b);
        __syncthreads();
    }

    // ---- merge: wave1 -> wave0 (select), wave3 -> wave2 (window) ----
    // mrg aliases the (now dead) tile memory.
    float* mrgf = smemf;   // [2][16*132]
    if (w == 1) {
        if (g == 0) { mlbuf[wv][c][0] = m_run; mlbuf[wv][c][1] = l_run; }
        float* dst = mrgf + (wv >> 1) * (16 * 132) + c * 132;
        #pragma unroll
        for (int dt = 0; dt < 8; ++dt)
            *reinterpret_cast<float4*>(dst + dt * 16 + g * 4) =
                (float4){o_acc[dt][0], o_acc[dt][1], o_acc[dt][2], o_acc[dt][3]};
    }
    __syncthreads();
    if (w == 0) {
        float m1 = mlbuf[wv + 1][c][0];
        float l1 = mlbuf[wv + 1][c][1];
        float mn = fmaxf(m_run, m1);
        float a0 = exp2f(m_run - mn), a1 = exp2f(m1 - mn);
        l_run = a0 * l_run + a1 * l1;
        float inv = 1.f / l_run;
        const float* src = mrgf + (wv >> 1) * (16 * 132) + c * 132;
        #pragma unroll
        for (int dt = 0; dt < 8; ++dt) {
            float4 o1 = *reinterpret_cast<const float4*>(src + dt * 16 + g * 4);
            o_acc[dt][0] = (a0 * o_acc[dt][0] + a1 * o1.x) * inv;
            o_acc[dt][1] = (a0 * o_acc[dt][1] + a1 * o1.y) * inv;
            o_acc[dt][2] = (a0 * o_acc[dt][2] + a1 * o1.z) * inv;
            o_acc[dt][3] = (a0 * o_acc[dt][3] + a1 * o1.w) * inv;
        }
    }
    // wave 2 publishes final (normalized) o_sw into mrg[1]
    if (wv == 2) {
        float* dst = mrgf + (16 * 132) + c * 132;
        #pragma unroll
        for (int dt = 0; dt < 8; ++dt)
            *reinterpret_cast<float4*>(dst + dt * 16 + g * 4) =
                (float4){o_acc[dt][0], o_acc[dt][1], o_acc[dt][2], o_acc[dt][3]};
    }
    __syncthreads();
    if (wv != 0) return;

    // ---- fusion epilogue (wave 0: o_sel in regs, o_sw in mrg[1], o_cmp in out) ----
    const float* owp = mrgf + (16 * 132) + c * 132;
    float4 oc[8], ow[8];
    #pragma unroll
    for (int dt = 0; dt < 8; ++dt) {
        oc[dt] = *reinterpret_cast<const float4*>(out + th * 1024 + hh * 128 + dt * 16 + g * 4);
        ow[dt] = *reinterpret_cast<const float4*>(owp + dt * 16 + g * 4);
    }
    const float* fwp = fw + hh * 3 * 384;
    float p0 = 0.f, p1 = 0.f, p2 = 0.f;
    #pragma unroll
    for (int dt = 0; dt < 8; ++dt) {
        #pragma unroll
        for (int i = 0; i < 4; ++i) {
            int d = dt * 16 + g * 4 + i;
            float a = (i == 0) ? oc[dt].x : (i == 1) ? oc[dt].y : (i == 2) ? oc[dt].z : oc[dt].w;
            float bsl = o_acc[dt][i];
            float cw = (i == 0) ? ow[dt].x : (i == 1) ? ow[dt].y : (i == 2) ? ow[dt].z : ow[dt].w;
            p0 += fwp[0 * 384 + d] * a + fwp[0 * 384 + 128 + d] * bsl + fwp[0 * 384 + 256 + d] * cw;
            p1 += fwp[1 * 384 + d] * a + fwp[1 * 384 + 128 + d] * bsl + fwp[1 * 384 + 256 + d] * cw;
            p2 += fwp[2 * 384 + d] * a + fwp[2 * 384 + 128 + d] * bsl + fwp[2 * 384 + 256 + d] * cw;
        }
    }
    p0 += __shfl_xor(p0, 16); p0 += __shfl_xor(p0, 32);
    p1 += __shfl_xor(p1, 16); p1 += __shfl_xor(p1, 32);
    p2 += __shfl_xor(p2, 16); p2 += __shfl_xor(p2, 32);
    float mx = fmaxf(p0, fmaxf(p1, p2));
    float e0 = expf(p0 - mx), e1 = expf(p1 - mx), e2 = expf(p2 - mx);
    float inv3 = 1.f / (e0 + e1 + e2);
    float w0 = e0 * inv3, w1 = e1 * inv3, w2 = e2 * inv3;
    #pragma unroll
    for (int dt = 0; dt < 8; ++dt) {
        float4 r;
        r.x = w0 * oc[dt].x + w1 * o_acc[dt][0] + w2 * ow[dt].x;
        r.y = w0 * oc[dt].y + w1 * o_acc[dt][1] + w2 * ow[dt].y;
        r.z = w0 * oc[dt].z + w1 * o_acc[dt][2] + w2 * ow[dt].z;
        r.w = w0 * oc[dt].w + w1 * o_acc[dt][3] + w2 * ow[dt].w;
        *reinterpret_cast<float4*>(out + th * 1024 + hh * 128 + dt * 16 + g * 4) = r;
    }
}

extern "C" void kernel_launch(void* const* d_in, const int* in_sizes, int n_in,
                              void* d_out, int out_size, void* d_ws, size_t ws_size,
                              hipStream_t stream) {
    (void)in_sizes; (void)n_in; (void)out_size; (void)ws_size;
    const float* q   = (const float*)d_in[0];
    const float* k   = (const float*)d_in[1];
    const float* v   = (const float*)d_in[2];
    const float* wk  = (const float*)d_in[3];
    const float* wvg = (const float*)d_in[4];
    const float* fw  = (const float*)d_in[5];
    float* out = (float*)d_out;
    float* ws = (float*)d_ws;
    float* ck = ws;
    float* cv = ws + NCMP * 128;
    unsigned int* selmask = (unsigned int*)(ws + 2 * NCMP * 128);
    unsigned short* kswz = (unsigned short*)(ws + 2 * NCMP * 128 + 2048);
    unsigned short* vswz = kswz + 2048 * 128;

    k_convert<<<dim3(256), dim3(256), 0, stream>>>(k, v, kswz, vswz);
    k_compress2<<<dim3(2 * NCMP), dim3(256), 0, stream>>>(k, v, wk, wvg, ck, cv);
    k_cmp_attn<<<dim3(2048 / TB), dim3(256), 0, stream>>>(q, ck, cv, out, selmask);
    k_main<<<dim3(1024), dim3(256), 0, stream>>>(q, kswz, vswz, selmask, fw, out);
}

// Round 13
// 184.903 us; speedup vs baseline: 1.3050x; 1.0455x over previous
//
#include <hip/hip_runtime.h>

// NSA constants
#define NCMP 127
#define SCALE 0.08838834764831845f
#define QSCALE (0.08838834764831845f * 1.4426950408889634f)  // SCALE * log2(e)
#define TB 4    // t's per WG in k_cmp_attn

typedef __attribute__((ext_vector_type(8))) short bf16x8;
typedef __attribute__((ext_vector_type(4))) float f32x4;

__device__ __forceinline__ unsigned short f2bf(float x) {
    union { float f; unsigned u; } a; a.f = x;
    unsigned r = a.u + 0x7fffu + ((a.u >> 16) & 1u);
    return (unsigned short)(r >> 16);
}
__device__ __forceinline__ float dot4(float4 a, float4 b) {
    return a.x * b.x + a.y * b.y + a.z * b.z + a.w * b.w;
}
__device__ __forceinline__ void gload_lds16(const void* g, void* l) {
    __builtin_amdgcn_global_load_lds(
        (const __attribute__((address_space(1))) unsigned int*)g,
        (__attribute__((address_space(3))) unsigned int*)l, 16, 0, 0);
}

// ------------- Kernel A: fused k+v compress (gate-pooled blocks) -------------
__global__ __launch_bounds__(256) void k_compress2(const float* __restrict__ kk,
                                                   const float* __restrict__ vv,
                                                   const float* __restrict__ wk,
                                                   const float* __restrict__ wv,
                                                   float* __restrict__ ck,
                                                   float* __restrict__ cv) {
    __shared__ float blk[4096];   // 32 x 128 f32
    __shared__ float gate[32];
    int n = blockIdx.x >> 1;
    int which = blockIdx.x & 1;
    const float* src = which ? vv : kk;
    const float* w   = which ? wv : wk;
    float* out       = which ? cv : ck;
    int tid = threadIdx.x;

    {
        const float4* sp = reinterpret_cast<const float4*>(src + n * 16 * 128);
        float4* bp = reinterpret_cast<float4*>(blk);
        #pragma unroll
        for (int i = 0; i < 4; ++i) bp[tid + 256 * i] = sp[tid + 256 * i];
    }
    __syncthreads();

    {
        int j = tid >> 3, sub = tid & 7;
        const float4* wp = reinterpret_cast<const float4*>(w + j * 4096);
        const float4* bp = reinterpret_cast<const float4*>(blk);
        float s0 = 0.f, s1 = 0.f, s2 = 0.f, s3 = 0.f;
        for (int i = sub * 4; i < 1024; i += 32) {
            float4 w0 = wp[i], w1 = wp[i + 1], w2 = wp[i + 2], w3 = wp[i + 3];
            s0 += dot4(bp[i], w0);
            s1 += dot4(bp[i + 1], w1);
            s2 += dot4(bp[i + 2], w2);
            s3 += dot4(bp[i + 3], w3);
        }
        float s = (s0 + s1) + (s2 + s3);
        s += __shfl_xor(s, 1);
        s += __shfl_xor(s, 2);
        s += __shfl_xor(s, 4);
        if (sub == 0) gate[j] = s;
    }
    __syncthreads();

    if (tid < 32) {
        float gv = gate[tid];
        float m = gv;
        #pragma unroll
        for (int off = 16; off > 0; off >>= 1) m = fmaxf(m, __shfl_xor(m, off));
        float e = expf(gv - m);
        float ss = e;
        #pragma unroll
        for (int off = 16; off > 0; off >>= 1) ss += __shfl_xor(ss, off);
        gate[tid] = e / ss;
    }
    __syncthreads();

    if (tid < 128) {
        float acc = 0.f;
        #pragma unroll
        for (int kx = 0; kx < 32; ++kx) acc += gate[kx] * blk[kx * 128 + tid];
        out[n * 128 + tid] = acc;
    }
}

// ---- Kernel D: f32 -> bf16 swizzled layouts (LDS-transposed V, coalesced writes) ----
// kswz: row-major [2048][128] bf16, byte offset within row XOR'd by ((row&7)<<4)
// vswz: blocked [32][128 d][64 p] bf16, byte offset within d-row XOR'd by ((d&7)<<4)
// grid 64: WG = half-block (32 rows / 32 positions)
__global__ __launch_bounds__(256) void k_convert(const float* __restrict__ k,
                                                 const float* __restrict__ v,
                                                 unsigned short* __restrict__ kswz,
                                                 unsigned short* __restrict__ vswz) {
    __shared__ unsigned short vl[32 * 132];   // [pl][d], pad 132 -> conflict-free transpose reads
    int wgid = blockIdx.x;
    int b = wgid >> 1, half = wgid & 1;
    int tid = threadIdx.x;
    int r0 = b * 64 + half * 32;

    // kswz: 32 rows x 128 d (same byte layout as before)
    #pragma unroll
    for (int it = 0; it < 4; ++it) {
        int idx = it * 1024 + tid * 4;
        int row = r0 + (idx >> 7), d = idx & 127;
        float4 x = *reinterpret_cast<const float4*>(k + r0 * 128 + idx);
        unsigned short o[4] = {f2bf(x.x), f2bf(x.y), f2bf(x.z), f2bf(x.w)};
        char* dst = (char*)kswz + row * 256 + ((d * 2) ^ ((row & 7) << 4));
        *reinterpret_cast<unsigned long long*>(dst) = *reinterpret_cast<unsigned long long*>(o);
    }

    // stage v half-block to LDS bf16
    #pragma unroll
    for (int it = 0; it < 4; ++it) {
        int idx = it * 1024 + tid * 4;
        int pl = idx >> 7, d = idx & 127;
        float4 x = *reinterpret_cast<const float4*>(v + r0 * 128 + idx);
        unsigned short o[4] = {f2bf(x.x), f2bf(x.y), f2bf(x.z), f2bf(x.w)};
        *reinterpret_cast<unsigned long long*>(&vl[pl * 132 + d]) =
            *reinterpret_cast<unsigned long long*>(o);
    }
    __syncthreads();

    // write vswz in 16B chunks. (pl*2)^((d&7)<<4) == (((pl>>3)^(d&7))<<4) | ((pl&7)*2)
    #pragma unroll
    for (int it = 0; it < 2; ++it) {
        int task = it * 256 + tid;          // 512 tasks = 128 d x 4 src-chunks
        int d = task >> 2, cjs = task & 3;
        int src_chunk = half * 4 + cjs;
        int dst_chunk = src_chunk ^ (d & 7);
        union { unsigned short s[8]; uint4 q; } u;
        #pragma unroll
        for (int i = 0; i < 8; ++i) u.s[i] = vl[(cjs * 8 + i) * 132 + d];
        char* dst = (char*)vswz + b * 16384 + d * 128 + dst_chunk * 16;
        *reinterpret_cast<uint4*>(dst) = u.q;
    }
}

// ---------- Kernel B: compressed attention + top-k block select (TB=4, 2 WG/CU) ----------
__global__ __launch_bounds__(256) void k_cmp_attn(const float* __restrict__ q,
                                                  const float* __restrict__ ck,
                                                  const float* __restrict__ cv,
                                                  float* __restrict__ o_cmp,
                                                  unsigned int* __restrict__ selmask) {
    __shared__ float sc[32 * 132];
    __shared__ float pg[TB * 128];
    __shared__ float slc[TB * 32];
    __shared__ float adj[TB * 32];
    int bid = blockIdx.x;
    int swz = (bid < 256) ? bid : (767 - bid);   // CU r gets swz {r, 511-r}: constant load sum
    int t0 = swz * TB;
    int tid = threadIdx.x;
    int wv = tid >> 6, ln = tid & 63;

    // ---- scores: 32 rows x 127 n; waves split rows(2) x n(2) ----
    {
        int rh = wv >> 1, nh = wv & 1;
        int rg = ln >> 3, ds = ln & 7;
        int d0 = ds * 16;
        float4 qr[2][4];
        #pragma unroll
        for (int rr = 0; rr < 2; ++rr) {
            int r = rh * 16 + rg * 2 + rr;
            const float4* qp = reinterpret_cast<const float4*>(
                q + (t0 + (r >> 3)) * 1024 + (r & 7) * 128 + d0);
            #pragma unroll
            for (int cc = 0; cc < 4; ++cc) qr[rr][cc] = qp[cc];
        }
        for (int jn = 0; jn < 64; ++jn) {
            int n = nh * 64 + jn;
            if (n >= NCMP) break;
            const float4* kp = reinterpret_cast<const float4*>(ck + n * 128 + d0);
            float4 k0 = kp[0], k1 = kp[1], k2 = kp[2], k3 = kp[3];
            float part[2];
            #pragma unroll
            for (int rr = 0; rr < 2; ++rr)
                part[rr] = dot4(qr[rr][0], k0) + dot4(qr[rr][1], k1) +
                           dot4(qr[rr][2], k2) + dot4(qr[rr][3], k3);
            #pragma unroll
            for (int off = 1; off < 8; off <<= 1)
                #pragma unroll
                for (int rr = 0; rr < 2; ++rr) part[rr] += __shfl_xor(part[rr], off);
            if (ds == 0) {
                #pragma unroll
                for (int rr = 0; rr < 2; ++rr)
                    sc[(rh * 16 + rg * 2 + rr) * 132 + n] = part[rr] * SCALE;
            }
        }
    }
    __syncthreads();

    // ---- mask + softmax per row (8 lanes per row) ----
    {
        int r = tid >> 3, nl = tid & 7;
        int t = t0 + (r >> 3);
        int nvalid = (t >= 31) ? (((t - 31) >> 4) + 1) : 0;
        if (nvalid > NCMP) nvalid = NCMP;
        float* row = sc + r * 132;
        float m = -3e38f;
        for (int n = nl; n < nvalid; n += 8) m = fmaxf(m, row[n]);
        m = fmaxf(m, __shfl_xor(m, 1));
        m = fmaxf(m, __shfl_xor(m, 2));
        m = fmaxf(m, __shfl_xor(m, 4));
        float ss = 0.f;
        for (int n = nl; n < 128; n += 8) {
            float e = (n < nvalid) ? expf(row[n] - m) : 0.f;
            ss += e;
            row[n] = e;
        }
        ss += __shfl_xor(ss, 1);
        ss += __shfl_xor(ss, 2);
        ss += __shfl_xor(ss, 4);
        float inv = (ss > 0.f) ? 1.f / ss : 0.f;
        for (int n = nl; n < 128; n += 8) row[n] *= inv;
    }
    __syncthreads();

    // ---- o_cmp: wave wv owns t = t0 + wv (loop only to its own nvalid) ----
    {
        int rg = ln >> 3, ds = ln & 7, d0 = ds * 16;
        int r = wv * 8 + rg;
        int t = t0 + wv;
        int nv = (t >= 31) ? (((t - 31) >> 4) + 1) : 0;
        if (nv > NCMP) nv = NCMP;
        float4 acc[4];
        #pragma unroll
        for (int cc = 0; cc < 4; ++cc) acc[cc] = (float4){0.f, 0.f, 0.f, 0.f};
        for (int n = 0; n < nv; ++n) {
            const float4* vp = reinterpret_cast<const float4*>(cv + n * 128 + d0);
            float4 v0 = vp[0], v1 = vp[1], v2 = vp[2], v3 = vp[3];
            float p = sc[r * 132 + n];
            acc[0].x += p * v0.x; acc[0].y += p * v0.y; acc[0].z += p * v0.z; acc[0].w += p * v0.w;
            acc[1].x += p * v1.x; acc[1].y += p * v1.y; acc[1].z += p * v1.z; acc[1].w += p * v1.w;
            acc[2].x += p * v2.x; acc[2].y += p * v2.y; acc[2].z += p * v2.z; acc[2].w += p * v2.w;
            acc[3].x += p * v3.x; acc[3].y += p * v3.y; acc[3].z += p * v3.z; acc[3].w += p * v3.w;
        }
        float4* op = reinterpret_cast<float4*>(o_cmp + t * 1024 + rg * 128 + d0);
        #pragma unroll
        for (int cc = 0; cc < 4; ++cc) op[cc] = acc[cc];
    }

    // ---- pg: sum probs over heads ----
    for (int i2 = tid; i2 < TB * 128; i2 += 256) {
        int tl = i2 >> 7, n = i2 & 127;
        float s = 0.f;
        #pragma unroll
        for (int h = 0; h < 8; ++h) s += sc[(tl * 8 + h) * 132 + n];
        pg[i2] = s;
    }
    __syncthreads();
    if (tid < TB * 32) {
        int tl = tid >> 5, s32 = tid & 31;
        float s = 0.f;
        #pragma unroll
        for (int j = 0; j < 4; ++j) {
            int n = s32 * 4 + j;
            if (n < NCMP) s += pg[tl * 128 + n];
        }
        slc[tid] = s;
    }
    __syncthreads();
    if (tid < TB) {
        int t = t0 + tid;
        int qblk = t >> 6;
        float* a = adj + tid * 32;
        for (int s = 0; s < 32; ++s) {
            if (s > qblk) a[s] = -1e30f;
            else a[s] = slc[tid * 32 + s] + ((s == 0 || s > qblk - 2) ? 1e30f : 0.f);
        }
        unsigned int msk = 0u;
        for (int it = 0; it < 16; ++it) {
            float best = -2e38f; int bi = 0;
            for (int s = 0; s < 32; ++s) { if (a[s] > best) { best = a[s]; bi = s; } }
            if (best <= -5e29f) break;
            msk |= 1u << bi;
            a[bi] = -2e38f;
        }
        selmask[t] = msk;
    }
}

// -------- Kernel C: 1 t-pair/WG, single 32KB LDS tile, 4 WG/CU (unchanged R12) --------
__global__ __launch_bounds__(256, 4) void k_main(const float* __restrict__ q,
                                              const unsigned short* __restrict__ kswz,
                                              const unsigned short* __restrict__ vswz,
                                              const unsigned int* __restrict__ selmask,
                                              const float* __restrict__ fw,
                                              float* __restrict__ out) {
    __shared__ float smemf[8192];      // 32KB tile; aliased by mrg after loop
    __shared__ float mlbuf[4][16][2];
    char* smem = (char*)smemf;

    int bid = blockIdx.x;
    int pairidx = (bid < 512) ? (1023 - bid) : (bid - 512);
    int tp = pairidx * 2;

    int tid = threadIdx.x;
    int wv = tid >> 6, ln = tid & 63;
    int c = ln & 15, g = ln >> 4;
    bool is_sel = (wv < 2);
    int w = wv & 1;

    unsigned int sm0 = selmask[tp], sm1 = selmask[tp + 1];
    unsigned int sm_wave = sm0 | sm1;

    int th = tp + (c >> 3);
    int hh = c & 7;
    unsigned int smc = (c >> 3) ? sm1 : sm0;

    bf16x8 qf[4];
    {
        const float* qp = q + th * 1024 + hh * 128;
        #pragma unroll
        for (int ks = 0; ks < 4; ++ks) {
            int d0 = ks * 32 + g * 8;
            float4 x = *reinterpret_cast<const float4*>(qp + d0);
            float4 y = *reinterpret_cast<const float4*>(qp + d0 + 4);
            bf16x8 f;
            f[0]=(short)f2bf(x.x*QSCALE); f[1]=(short)f2bf(x.y*QSCALE); f[2]=(short)f2bf(x.z*QSCALE); f[3]=(short)f2bf(x.w*QSCALE);
            f[4]=(short)f2bf(y.x*QSCALE); f[5]=(short)f2bf(y.y*QSCALE); f[6]=(short)f2bf(y.z*QSCALE); f[7]=(short)f2bf(y.w*QSCALE);
            qf[ks] = f;
        }
    }

    float m_run = -1e30f, l_run = 0.f;
    f32x4 o_acc[8];
    #pragma unroll
    for (int dt = 0; dt < 8; ++dt) o_acc[dt] = (f32x4){0.f, 0.f, 0.f, 0.f};

    int qblk_max = (tp + 1) >> 6;
    int wlo = (tp >= 575) ? (((tp - 575) >> 6) + 1) : 0;
    unsigned int all = (qblk_max >= 31) ? 0xFFFFFFFFu : ((1u << (qblk_max + 1)) - 1u);
    unsigned int wmask = all & ~((1u << wlo) - 1u);
    unsigned int mm = (sm_wave & all) | wmask;

    int srcA = ((g & 1) << 5) + c;
    int srcB = srcA + 16;
    bool hi = (g >= 2);

    auto stage = [&](int b) {
        const char* ks = (const char*)kswz + b * 16384;
        const char* vs = (const char*)vswz + b * 16384;
        char* kd = smem;
        char* vd = smem + 16384;
        int lo = wv * 1024;
        int so = lo + ln * 16;
        #pragma unroll
        for (int j = 0; j < 4; ++j) {
            gload_lds16(ks + j * 4096 + so, kd + j * 4096 + lo);
            gload_lds16(vs + j * 4096 + so, vd + j * 4096 + lo);
        }
    };

    auto compute = [&](int b) {
        const char* kl = smem;
        const char* vl = smem + 16384;
        int z = (c & 7) << 4;

        f32x4 sacc[4];
        #pragma unroll
        for (int nt = 0; nt < 4; ++nt) {
            f32x4 acc = (f32x4){0.f, 0.f, 0.f, 0.f};
            #pragma unroll
            for (int ks = 0; ks < 4; ++ks) {
                bf16x8 kf = *reinterpret_cast<const bf16x8*>(
                    kl + (nt * 16 + c) * 256 + ((ks * 64 + g * 16) ^ z));
                acc = __builtin_amdgcn_mfma_f32_16x16x32_bf16(kf, qf[ks], acc, 0, 0, 0);
            }
            sacc[nt] = acc;
        }

        bool selbit = (smc >> b) & 1u;
        float mloc = -1e30f;
        #pragma unroll
        for (int nt = 0; nt < 4; ++nt) {
            #pragma unroll
            for (int i = 0; i < 4; ++i) {
                int pos = b * 64 + nt * 16 + g * 4 + i;
                bool val;
                if (is_sel) val = selbit && (pos <= th);
                else        val = (pos <= th) && (pos + 512 > th);
                float s = val ? sacc[nt][i] : -1e30f;
                sacc[nt][i] = s;
                mloc = fmaxf(mloc, s);
            }
        }
        mloc = fmaxf(mloc, __shfl_xor(mloc, 16));
        mloc = fmaxf(mloc, __shfl_xor(mloc, 32));
        float mn = fmaxf(m_run, mloc);
        float al = exp2f(m_run - mn);

        float lsum = 0.f;
        #pragma unroll
        for (int nt = 0; nt < 4; ++nt) {
            #pragma unroll
            for (int i = 0; i < 4; ++i) {
                float s = sacc[nt][i];
                float p = (s > -5e29f) ? exp2f(s - mn) : 0.f;
                sacc[nt][i] = p;
                lsum += p;
            }
        }
        lsum += __shfl_xor(lsum, 16);
        lsum += __shfl_xor(lsum, 32);
        m_run = mn;
        l_run = l_run * al + lsum;

        if (__any(al != 1.f)) {
            #pragma unroll
            for (int dt = 0; dt < 8; ++dt)
                #pragma unroll
                for (int i = 0; i < 4; ++i)
                    o_acc[dt][i] *= al;
        }

        unsigned int pw[8];
        #pragma unroll
        for (int nt = 0; nt < 4; ++nt) {
            unsigned int w0, w1;
            asm("v_cvt_pk_bf16_f32 %0, %1, %2" : "=v"(w0) : "v"(sacc[nt][0]), "v"(sacc[nt][1]));
            asm("v_cvt_pk_bf16_f32 %0, %1, %2" : "=v"(w1) : "v"(sacc[nt][2]), "v"(sacc[nt][3]));
            pw[2 * nt] = w0;
            pw[2 * nt + 1] = w1;
        }

        #pragma unroll
        for (int ks = 0; ks < 2; ++ks) {
            unsigned int a0 = __shfl(pw[4 * ks + 0], srcA);
            unsigned int a1 = __shfl(pw[4 * ks + 1], srcA);
            unsigned int a2 = __shfl(pw[4 * ks + 0], srcB);
            unsigned int a3 = __shfl(pw[4 * ks + 1], srcB);
            unsigned int b0 = __shfl(pw[4 * ks + 2], srcA);
            unsigned int b1 = __shfl(pw[4 * ks + 3], srcA);
            unsigned int b2 = __shfl(pw[4 * ks + 2], srcB);
            unsigned int b3 = __shfl(pw[4 * ks + 3], srcB);
            unsigned int wparr[4] = {hi ? b0 : a0, hi ? b1 : a1, hi ? b2 : a2, hi ? b3 : a3};
            bf16x8 pa = *reinterpret_cast<bf16x8*>(wparr);
            #pragma unroll
            for (int dt = 0; dt < 8; ++dt) {
                bf16x8 vfr = *reinterpret_cast<const bf16x8*>(
                    vl + (dt * 16 + c) * 128 + ((ks * 64 + g * 16) ^ z));
                o_acc[dt] = __builtin_amdgcn_mfma_f32_16x16x32_bf16(vfr, pa, o_acc[dt], 0, 0, 0);
            }
        }
    };

    int selidx = 0, winidx = 0;
    while (mm) {
        int b = __builtin_ctz(mm);
        mm &= mm - 1;
        stage(b);
        __syncthreads();
        bool act;
        if (is_sel) {
            bool sb = (sm_wave >> b) & 1u;
            act = sb && ((selidx & 1) == w);
            selidx += sb ? 1 : 0;
        } else {
            bool wb = (b * 64 + 575 > tp);
            act = wb && ((winidx & 1) == w);
            winidx += wb ? 1 : 0;
        }
        if (act) compute(b);
        __syncthreads();
    }

    float* mrgf = smemf;
    if (w == 1) {
        if (g == 0) { mlbuf[wv][c][0] = m_run; mlbuf[wv][c][1] = l_run; }
        float* dst = mrgf + (wv >> 1) * (16 * 132) + c * 132;
        #pragma unroll
        for (int dt = 0; dt < 8; ++dt)
            *reinterpret_cast<float4*>(dst + dt * 16 + g * 4) =
                (float4){o_acc[dt][0], o_acc[dt][1], o_acc[dt][2], o_acc[dt][3]};
    }
    __syncthreads();
    if (w == 0) {
        float m1 = mlbuf[wv + 1][c][0];
        float l1 = mlbuf[wv + 1][c][1];
        float mn = fmaxf(m_run, m1);
        float a0 = exp2f(m_run - mn), a1 = exp2f(m1 - mn);
        l_run = a0 * l_run + a1 * l1;
        float inv = 1.f / l_run;
        const float* src = mrgf + (wv >> 1) * (16 * 132) + c * 132;
        #pragma unroll
        for (int dt = 0; dt < 8; ++dt) {
            float4 o1 = *reinterpret_cast<const float4*>(src + dt * 16 + g * 4);
            o_acc[dt][0] = (a0 * o_acc[dt][0] + a1 * o1.x) * inv;
            o_acc[dt][1] = (a0 * o_acc[dt][1] + a1 * o1.y) * inv;
            o_acc[dt][2] = (a0 * o_acc[dt][2] + a1 * o1.z) * inv;
            o_acc[dt][3] = (a0 * o_acc[dt][3] + a1 * o1.w) * inv;
        }
    }
    if (wv == 2) {
        float* dst = mrgf + (16 * 132) + c * 132;
        #pragma unroll
        for (int dt = 0; dt < 8; ++dt)
            *reinterpret_cast<float4*>(dst + dt * 16 + g * 4) =
                (float4){o_acc[dt][0], o_acc[dt][1], o_acc[dt][2], o_acc[dt][3]};
    }
    __syncthreads();
    if (wv != 0) return;

    const float* owp = mrgf + (16 * 132) + c * 132;
    float4 oc[8], ow[8];
    #pragma unroll
    for (int dt = 0; dt < 8; ++dt) {
        oc[dt] = *reinterpret_cast<const float4*>(out + th * 1024 + hh * 128 + dt * 16 + g * 4);
        ow[dt] = *reinterpret_cast<const float4*>(owp + dt * 16 + g * 4);
    }
    const float* fwp = fw + hh * 3 * 384;
    float p0 = 0.f, p1 = 0.f, p2 = 0.f;
    #pragma unroll
    for (int dt = 0; dt < 8; ++dt) {
        #pragma unroll
        for (int i = 0; i < 4; ++i) {
            int d = dt * 16 + g * 4 + i;
            float a = (i == 0) ? oc[dt].x : (i == 1) ? oc[dt].y : (i == 2) ? oc[dt].z : oc[dt].w;
            float bsl = o_acc[dt][i];
            float cw = (i == 0) ? ow[dt].x : (i == 1) ? ow[dt].y : (i == 2) ? ow[dt].z : ow[dt].w;
            p0 += fwp[0 * 384 + d] * a + fwp[0 * 384 + 128 + d] * bsl + fwp[0 * 384 + 256 + d] * cw;
            p1 += fwp[1 * 384 + d] * a + fwp[1 * 384 + 128 + d] * bsl + fwp[1 * 384 + 256 + d] * cw;
            p2 += fwp[2 * 384 + d] * a + fwp[2 * 384 + 128 + d] * bsl + fwp[2 * 384 + 256 + d] * cw;
        }
    }
    p0 += __shfl_xor(p0, 16); p0 += __shfl_xor(p0, 32);
    p1 += __shfl_xor(p1, 16); p1 += __shfl_xor(p1, 32);
    p2 += __shfl_xor(p2, 16); p2 += __shfl_xor(p2, 32);
    float mx = fmaxf(p0, fmaxf(p1, p2));
    float e0 = expf(p0 - mx), e1 = expf(p1 - mx), e2 = expf(p2 - mx);
    float inv3 = 1.f / (e0 + e1 + e2);
    float w0 = e0 * inv3, w1 = e1 * inv3, w2 = e2 * inv3;
    #pragma unroll
    for (int dt = 0; dt < 8; ++dt) {
        float4 r;
        r.x = w0 * oc[dt].x + w1 * o_acc[dt][0] + w2 * ow[dt].x;
        r.y = w0 * oc[dt].y + w1 * o_acc[dt][1] + w2 * ow[dt].y;
        r.z = w0 * oc[dt].z + w1 * o_acc[dt][2] + w2 * ow[dt].z;
        r.w = w0 * oc[dt].w + w1 * o_acc[dt][3] + w2 * ow[dt].w;
        *reinterpret_cast<float4*>(out + th * 1024 + hh * 128 + dt * 16 + g * 4) = r;
    }
}

extern "C" void kernel_launch(void* const* d_in, const int* in_sizes, int n_in,
                              void* d_out, int out_size, void* d_ws, size_t ws_size,
                              hipStream_t stream) {
    (void)in_sizes; (void)n_in; (void)out_size; (void)ws_size;
    const float* q   = (const float*)d_in[0];
    const float* k   = (const float*)d_in[1];
    const float* v   = (const float*)d_in[2];
    const float* wk  = (const float*)d_in[3];
    const float* wvg = (const float*)d_in[4];
    const float* fw  = (const float*)d_in[5];
    float* out = (float*)d_out;
    float* ws = (float*)d_ws;
    float* ck = ws;
    float* cv = ws + NCMP * 128;
    unsigned int* selmask = (unsigned int*)(ws + 2 * NCMP * 128);
    unsigned short* kswz = (unsigned short*)(ws + 2 * NCMP * 128 + 2048);
    unsigned short* vswz = kswz + 2048 * 128;

    k_convert<<<dim3(64), dim3(256), 0, stream>>>(k, v, kswz, vswz);
    k_compress2<<<dim3(2 * NCMP), dim3(256), 0, stream>>>(k, v, wk, wvg, ck, cv);
    k_cmp_attn<<<dim3(512), dim3(256), 0, stream>>>(q, ck, cv, out, selmask);
    k_main<<<dim3(1024), dim3(256), 0, stream>>>(q, kswz, vswz, selmask, fw, out);
}